// Round 5
// baseline (1803.777 us; speedup 1.0000x reference)
//
#include <hip/hip_runtime.h>
#include <hip/hip_bf16.h>

typedef __hip_bfloat16 bf16;

#define NB 16
#define NT 1024
#define ND 500
#define NTOK (NB * NT)
#define INV_SCALE 0.04472135954999579f   /* 1/sqrt(500) */

__device__ __forceinline__ float b2f(bf16 x) { return __bfloat162float(x); }

/* ---------------- K1: build g (B,T,500) bf16 from fp32 inputs ---------------- */
__global__ void build_g(const int* __restrict__ words, const int* __restrict__ pos,
                        const int* __restrict__ ner, const int* __restrict__ chunks,
                        const int* __restrict__ subj_pos, const int* __restrict__ obj_pos,
                        const int* __restrict__ on_path, const float* __restrict__ dep_feat,
                        const float* __restrict__ emb_w, const float* __restrict__ pos_w,
                        const float* __restrict__ ner_w, const float* __restrict__ chunk_w,
                        const float* __restrict__ position_w, bf16* __restrict__ g) {
    int tok = blockIdx.x;
    int w = words[tok], p = pos[tok], n = ner[tok], ck = chunks[tok];
    int sp = subj_pos[tok], op = obj_pos[tok], onp = on_path[tok];
    bf16* gr = g + (size_t)tok * ND;
    for (int d = threadIdx.x; d < ND; d += blockDim.x) {
        float v;
        if      (d < 300) v = emb_w[(size_t)w * 300 + d];
        else if (d < 335) v = pos_w[p * 35 + (d - 300)];
        else if (d < 365) v = ner_w[n * 30 + (d - 335)];
        else if (d < 395) v = chunk_w[ck * 30 + (d - 365)];
        else if (d < 425) v = position_w[sp * 30 + (d - 395)];
        else if (d < 455) v = position_w[op * 30 + (d - 425)];
        else if (d == 455) v = (float)onp;
        else              v = dep_feat[(size_t)tok * 44 + (d - 456)];
        gr[d] = __float2bfloat16(v);
    }
}

/* ---------------- K2: subj/obj max pool -> subj (B,500) fp32 ---------------- */
__global__ void subj_pool(const bf16* __restrict__ g, const int* __restrict__ subj_pos,
                          float* __restrict__ subj) {
    int b = blockIdx.x, d = threadIdx.x;
    if (d >= ND) return;
    float acc = -INFINITY;
    for (int t = 0; t < NT; t++) {
        int masked = (subj_pos[b * NT + t] != 0);
        float v = masked ? -1e12f : b2f(g[((size_t)(b * NT + t)) * ND + d]);
        acc = fmaxf(acc, v);
    }
    subj[b * ND + d] = acc;
}

/* ---------------- K3: q = relu(so @ Wq + bq), so=[subj,subj] ---------------- */
__global__ void compute_q(const float* __restrict__ subj, const float* __restrict__ Wq,
                          const float* __restrict__ bq, float* __restrict__ q) {
    int b = blockIdx.x, d = threadIdx.x;
    if (d >= ND) return;
    float acc = bq[d];
    for (int j = 0; j < ND; j++) {
        float s = subj[b * ND + j];
        acc += s * (Wq[(size_t)j * ND + d] + Wq[(size_t)(j + ND) * ND + d]);
    }
    q[b * ND + d] = fmaxf(acc, 0.f);
}

/* ---------------- K4: t = relu(q @ Wc[:500] + bc); w2 = t * Wk ---------------- */
__global__ void compute_t_w2(const float* __restrict__ q, const float* __restrict__ Wc,
                             const float* __restrict__ bc, const float* __restrict__ Wk,
                             float* __restrict__ w2) {
    int b = blockIdx.x, d = threadIdx.x;
    if (d >= ND) return;
    float acc = bc[d];
    for (int j = 0; j < ND; j++)
        acc += q[b * ND + j] * Wc[(size_t)j * ND + d];
    float tv = fmaxf(acc, 0.f);
    w2[b * ND + d] = tv * Wk[d];
}

/* ---------------- K5: k_logits[b,t] = dot(g[b,t,:], w2[b,:]) + bk ---------------- */
__global__ void compute_klog(const bf16* __restrict__ g, const float* __restrict__ w2,
                             const float* __restrict__ Wk_b, float* __restrict__ klog) {
    int tok = blockIdx.x;
    int b = tok >> 10;
    int lane = threadIdx.x;
    const bf16* gr = g + (size_t)tok * ND;
    const float* wr = w2 + b * ND;
    float acc = 0.f;
    for (int d = lane; d < ND; d += 64) acc += b2f(gr[d]) * wr[d];
    #pragma unroll
    for (int off = 32; off; off >>= 1) acc += __shfl_down(acc, off, 64);
    if (lane == 0) klog[tok] = acc + Wk_b[0];
}

/* ---------------- K6a: k = softmax(klog) over T per b ---------------- */
__global__ void softmax_k(const float* __restrict__ klog, float* __restrict__ k) {
    int b = blockIdx.x, tid = threadIdx.x;   /* 256 threads */
    __shared__ float red[256];
    float m = -INFINITY;
    for (int t = tid; t < NT; t += 256) m = fmaxf(m, klog[b * NT + t]);
    red[tid] = m; __syncthreads();
    for (int s = 128; s; s >>= 1) { if (tid < s) red[tid] = fmaxf(red[tid], red[tid + s]); __syncthreads(); }
    m = red[0]; __syncthreads();
    float sum = 0.f;
    for (int t = tid; t < NT; t += 256) sum += expf(klog[b * NT + t] - m);
    red[tid] = sum; __syncthreads();
    for (int s = 128; s; s >>= 1) { if (tid < s) red[tid] += red[tid + s]; __syncthreads(); }
    float inv = 1.f / red[0];
    for (int t = tid; t < NT; t += 256) k[b * NT + t] = expf(klog[b * NT + t] - m) * inv;
}

/* ---------------- K6b: c[b,d] = sum_t k[b,t]*g[b,t,d] ---------------- */
__global__ void compute_c(const bf16* __restrict__ g, const float* __restrict__ k,
                          float* __restrict__ c) {
    int b = blockIdx.x, d = threadIdx.x;
    if (d >= ND) return;
    float acc = 0.f;
    for (int t = 0; t < NT; t++)
        acc += k[b * NT + t] * b2f(g[((size_t)(b * NT + t)) * ND + d]);
    c[b * ND + d] = acc;
}

/* ---------------- K7: m = relu([c,subj,subj] @ Wm + bm) ---------------- */
__global__ void compute_m(const float* __restrict__ c, const float* __restrict__ subj,
                          const float* __restrict__ Wm, const float* __restrict__ bm,
                          float* __restrict__ mvec) {
    int b = blockIdx.x, d = threadIdx.x;
    if (d >= ND) return;
    float acc = bm[d];
    for (int j = 0; j < ND; j++) {
        acc += c[b * ND + j] * Wm[(size_t)j * ND + d];
        acc += subj[b * ND + j] * (Wm[(size_t)(ND + j) * ND + d] + Wm[(size_t)(2 * ND + j) * ND + d]);
    }
    mvec[b * ND + d] = fmaxf(acc, 0.f);
}

/* ---- K8: C(M,500) = A(M,500)bf16 @ W(500,500)fp32 + bias -> fp32 (tiled SIMT) ---- */
#define BM 64
#define BN 64
#define BK 16
__global__ void gemm_proj(const bf16* __restrict__ A, const float* __restrict__ W,
                          const float* __restrict__ bias, float* __restrict__ C) {
    __shared__ float As[BK][BM + 4];
    __shared__ float Bs[BK][BN + 4];
    int row0 = blockIdx.x * BM, col0 = blockIdx.y * BN;
    int tid = threadIdx.x;
    int tx = tid & 15, ty = tid >> 4;
    float acc[4][4] = {};
    for (int k0 = 0; k0 < ND; k0 += BK) {
        for (int i = tid; i < BM * BK; i += 256) {
            int r = i >> 4, kk = i & 15;
            int kidx = k0 + kk;
            As[kk][r] = (kidx < ND) ? b2f(A[(size_t)(row0 + r) * ND + kidx]) : 0.f;
        }
        for (int i = tid; i < BK * BN; i += 256) {
            int kk = i >> 6, n = i & 63;
            int kidx = k0 + kk, col = col0 + n;
            Bs[kk][n] = (kidx < ND && col < ND) ? W[(size_t)kidx * ND + col] : 0.f;
        }
        __syncthreads();
        #pragma unroll
        for (int kk = 0; kk < BK; kk++) {
            float4 av = *(const float4*)&As[kk][ty * 4];
            float4 bv = *(const float4*)&Bs[kk][tx * 4];
            float a[4] = {av.x, av.y, av.z, av.w};
            float bb[4] = {bv.x, bv.y, bv.z, bv.w};
            #pragma unroll
            for (int i = 0; i < 4; i++)
                #pragma unroll
                for (int j = 0; j < 4; j++) acc[i][j] += a[i] * bb[j];
        }
        __syncthreads();
    }
    for (int i = 0; i < 4; i++) {
        int r = row0 + ty * 4 + i;
        for (int j = 0; j < 4; j++) {
            int col = col0 + tx * 4 + j;
            if (col < ND) C[(size_t)r * ND + col] = acc[i][j] + bias[col];
        }
    }
}

/* ---- K9: Sc[z] = keyc[z] @ queryc[z]^T ---- */
__global__ void gemm_S(const float* __restrict__ keyc, const float* __restrict__ queryc,
                       float* __restrict__ Sc) {
    __shared__ float As[BK][BM + 4];
    __shared__ float Bs[BK][BN + 4];
    int z = blockIdx.z;
    int row0 = blockIdx.x * BM, col0 = blockIdx.y * BN;
    const float* A = keyc + (size_t)z * NT * ND;
    const float* Bq = queryc + (size_t)z * NT * ND;
    float* Sb = Sc + ((size_t)z << 20);
    int tid = threadIdx.x;
    int tx = tid & 15, ty = tid >> 4;
    float acc[4][4] = {};
    for (int k0 = 0; k0 < ND; k0 += BK) {
        for (int i = tid; i < BM * BK; i += 256) {
            int r = i >> 4, kk = i & 15;
            int kidx = k0 + kk;
            As[kk][r] = (kidx < ND) ? A[(size_t)(row0 + r) * ND + kidx] : 0.f;
        }
        for (int i = tid; i < BN * BK; i += 256) {
            int n = i >> 4, kk = i & 15;
            int kidx = k0 + kk;
            Bs[kk][n] = (kidx < ND) ? Bq[(size_t)(col0 + n) * ND + kidx] : 0.f;
        }
        __syncthreads();
        #pragma unroll
        for (int kk = 0; kk < BK; kk++) {
            float4 av = *(const float4*)&As[kk][ty * 4];
            float4 bv = *(const float4*)&Bs[kk][tx * 4];
            float a[4] = {av.x, av.y, av.z, av.w};
            float bb[4] = {bv.x, bv.y, bv.z, bv.w};
            #pragma unroll
            for (int i = 0; i < 4; i++)
                #pragma unroll
                for (int j = 0; j < 4; j++) acc[i][j] += a[i] * bb[j];
        }
        __syncthreads();
    }
    for (int i = 0; i < 4; i++) {
        size_t r = row0 + ty * 4 + i;
        for (int j = 0; j < 4; j++)
            Sb[(r << 10) + col0 + tx * 4 + j] = acc[i][j];
    }
}

/* ---- K10: per-row double softmax on Sc; att out fp32; overwrite Sc with P2 ---- */
__global__ void attn_rows(float* __restrict__ Sc, float* __restrict__ att_out, int b0) {
    int tokc = blockIdx.x;
    int z = tokc >> 10, t = tokc & 1023;
    float* row = Sc + ((size_t)z << 20) + ((size_t)t << 10);
    int tid = threadIdx.x;   /* 256 */
    __shared__ float red[256];
    __shared__ float diag;
    float v[4];
    #pragma unroll
    for (int i = 0; i < 4; i++) v[i] = row[i * 256 + tid];
    float m = fmaxf(fmaxf(v[0], v[1]), fmaxf(v[2], v[3]));
    red[tid] = m; __syncthreads();
    for (int s = 128; s; s >>= 1) { if (tid < s) red[tid] = fmaxf(red[tid], red[tid + s]); __syncthreads(); }
    m = red[0]; __syncthreads();
    float e1[4], e2[4], s1 = 0.f, s2 = 0.f;
    #pragma unroll
    for (int i = 0; i < 4; i++) {
        e1[i] = expf(v[i] - m);
        e2[i] = expf((v[i] - m) * INV_SCALE);
        s1 += e1[i]; s2 += e2[i];
        if (i * 256 + tid == t) diag = e1[i];
    }
    red[tid] = s1; __syncthreads();
    for (int s = 128; s; s >>= 1) { if (tid < s) red[tid] += red[tid + s]; __syncthreads(); }
    s1 = red[0]; __syncthreads();
    red[tid] = s2; __syncthreads();
    for (int s = 128; s; s >>= 1) { if (tid < s) red[tid] += red[tid + s]; __syncthreads(); }
    s2 = red[0]; __syncthreads();
    if (tid == 0) att_out[(size_t)(b0 + z) * NT + t] = (1.f - diag / s1) * INV_SCALE;
    float inv2 = 1.f / s2;
    #pragma unroll
    for (int i = 0; i < 4; i++) row[i * 256 + tid] = e2[i] * inv2;
}

/* ---- K11: out[b0+z] = P2[z] @ V[z]; epilogue *= mvec; fp32 store ---- */
__global__ void gemm_PV(const float* __restrict__ Sc, const float* __restrict__ valuec,
                        const float* __restrict__ mvec, float* __restrict__ outp, int b0) {
    __shared__ float As[BK][BM + 4];
    __shared__ float Bs[BK][BN + 4];
    int z = blockIdx.z;
    int row0 = blockIdx.x * BM, col0 = blockIdx.y * BN;
    const float* A = Sc + ((size_t)z << 20);
    const float* Bv = valuec + (size_t)z * NT * ND;
    int tid = threadIdx.x;
    int tx = tid & 15, ty = tid >> 4;
    float acc[4][4] = {};
    for (int k0 = 0; k0 < NT; k0 += BK) {
        for (int i = tid; i < BM * BK; i += 256) {
            int r = i >> 4, kk = i & 15;
            As[kk][r] = A[(((size_t)(row0 + r)) << 10) + k0 + kk];
        }
        for (int i = tid; i < BK * BN; i += 256) {
            int kk = i >> 6, n = i & 63;
            int col = col0 + n;
            Bs[kk][n] = (col < ND) ? Bv[(size_t)(k0 + kk) * ND + col] : 0.f;
        }
        __syncthreads();
        #pragma unroll
        for (int kk = 0; kk < BK; kk++) {
            float4 av = *(const float4*)&As[kk][ty * 4];
            float4 bv = *(const float4*)&Bs[kk][tx * 4];
            float a[4] = {av.x, av.y, av.z, av.w};
            float bb[4] = {bv.x, bv.y, bv.z, bv.w};
            #pragma unroll
            for (int i = 0; i < 4; i++)
                #pragma unroll
                for (int j = 0; j < 4; j++) acc[i][j] += a[i] * bb[j];
        }
        __syncthreads();
    }
    int gb = b0 + z;
    for (int i = 0; i < 4; i++) {
        int r = row0 + ty * 4 + i;
        for (int j = 0; j < 4; j++) {
            int col = col0 + tx * 4 + j;
            if (col < ND)
                outp[((size_t)gb * NT + r) * ND + col] = acc[i][j] * mvec[gb * ND + col];
        }
    }
}

extern "C" void kernel_launch(void* const* d_in, const int* in_sizes, int n_in,
                              void* d_out, int out_size, void* d_ws, size_t ws_size,
                              hipStream_t stream) {
    const int*   words     = (const int*)d_in[0];
    const int*   pos       = (const int*)d_in[2];
    const int*   ner       = (const int*)d_in[3];
    const int*   subj_pos  = (const int*)d_in[4];
    const int*   obj_pos   = (const int*)d_in[5];
    const int*   chunks    = (const int*)d_in[6];
    const int*   on_path   = (const int*)d_in[7];
    const float* dep_feat  = (const float*)d_in[8];
    const float* emb_w     = (const float*)d_in[9];
    const float* pos_w     = (const float*)d_in[10];
    const float* ner_w     = (const float*)d_in[11];
    const float* chunk_w   = (const float*)d_in[12];
    const float* position_w= (const float*)d_in[13];
    const float* Wq_w      = (const float*)d_in[14];
    const float* Wq_b      = (const float*)d_in[15];
    const float* Wc_w      = (const float*)d_in[16];
    const float* Wc_b      = (const float*)d_in[17];
    const float* Wk_w      = (const float*)d_in[18];
    const float* Wk_b      = (const float*)d_in[19];
    const float* Wm_w      = (const float*)d_in[20];
    const float* Wm_b      = (const float*)d_in[21];
    const float* K_w       = (const float*)d_in[22];
    const float* K_b       = (const float*)d_in[23];
    const float* Q_w       = (const float*)d_in[24];
    const float* Q_b       = (const float*)d_in[25];
    const float* V_w       = (const float*)d_in[26];
    const float* V_b       = (const float*)d_in[27];

    /* ---- outputs: fp32. out0 (B,T,D) then att (B,T) ---- */
    float* out_main = (float*)d_out;
    float* out_att  = out_main + (size_t)NTOK * ND;

    /* g (bf16, NTOK*ND elems = 16.38 MB) lives in d_out bytes [16.38 MB, 32.77 MB):
       ascending-chunk order guarantees g[b] is read (projections) before gemm_PV's
       fp32 write front reaches it: writes after chunk end b_end cover
       [0, b_end*2.048 MB) and g[b_end] starts at 16.38 + b_end*1.024 MB. */
    bf16* g = (bf16*)d_out + (size_t)NTOK * ND;

    /* ---- ws layout: [smalls (~0.3 MB) | chunk buffers] ---- */
    float* subj  = (float*)d_ws;
    float* qb    = subj + NB * ND;
    float* w2    = qb   + NB * ND;
    float* cb    = w2   + NB * ND;
    float* mv    = cb   + NB * ND;
    float* klog  = mv   + NB * ND;       /* NB*NT */
    float* kbuf  = klog + NB * NT;       /* NB*NT */
    float* chunk0 = kbuf + NB * NT;

    size_t fixed_bytes = (size_t)(5 * NB * ND + 2 * NB * NT) * 4;
    size_t per_batch   = ((size_t)3 * NT * ND + (size_t)NT * NT) * 4;  /* ~10.34 MB */
    int nbc = 1;
    {
        const int cand[5] = {16, 8, 4, 2, 1};
        for (int ci = 0; ci < 5; ci++) {
            if (fixed_bytes + (size_t)cand[ci] * per_batch <= ws_size) { nbc = cand[ci]; break; }
        }
    }
    float* keyc   = chunk0;
    float* queryc = keyc   + (size_t)nbc * NT * ND;
    float* valuec = queryc + (size_t)nbc * NT * ND;
    float* Sc     = valuec + (size_t)nbc * NT * ND;  /* nbc*NT*NT */

    /* ---- phase A: g + dense chain (full batch) ---- */
    build_g<<<NTOK, 128, 0, stream>>>(words, pos, ner, chunks, subj_pos, obj_pos,
                                      on_path, dep_feat, emb_w, pos_w, ner_w,
                                      chunk_w, position_w, g);
    subj_pool<<<NB, 512, 0, stream>>>(g, subj_pos, subj);
    compute_q<<<NB, 512, 0, stream>>>(subj, Wq_w, Wq_b, qb);
    compute_t_w2<<<NB, 512, 0, stream>>>(qb, Wc_w, Wc_b, Wk_w, w2);
    compute_klog<<<NTOK, 64, 0, stream>>>(g, w2, Wk_b, klog);
    softmax_k<<<NB, 256, 0, stream>>>(klog, kbuf);
    compute_c<<<NB, 512, 0, stream>>>(g, kbuf, cb);
    compute_m<<<NB, 512, 0, stream>>>(cb, subj, Wm_w, Wm_b, mv);

    /* ---- phase B: attention, nbc batches per chunk, ascending b0 ---- */
    dim3 gproj((nbc * NT) / BM, (ND + BN - 1) / BN);
    dim3 gS(NT / BM, NT / BN, nbc);
    dim3 gPV(NT / BM, (ND + BN - 1) / BN, nbc);
    for (int b0 = 0; b0 < NB; b0 += nbc) {
        const bf16* gch = g + (size_t)b0 * NT * ND;
        gemm_proj<<<gproj, 256, 0, stream>>>(gch, K_w, K_b, keyc);
        gemm_proj<<<gproj, 256, 0, stream>>>(gch, Q_w, Q_b, queryc);
        gemm_proj<<<gproj, 256, 0, stream>>>(gch, V_w, V_b, valuec);
        gemm_S<<<gS, 256, 0, stream>>>(keyc, queryc, Sc);
        attn_rows<<<nbc * NT, 256, 0, stream>>>(Sc, out_att, b0);
        gemm_PV<<<gPV, 256, 0, stream>>>(Sc, valuec, mv, out_main, b0);
    }

    (void)in_sizes; (void)n_in; (void)out_size;
}

// Round 6
// 594.572 us; speedup vs baseline: 3.0337x; 3.0337x over previous
//
#include <hip/hip_runtime.h>
#include <hip/hip_bf16.h>

typedef __hip_bfloat16 bf16;
typedef __attribute__((ext_vector_type(8))) short short8;
typedef __attribute__((ext_vector_type(4))) float f32x4;

#define NB 16
#define NT 1024
#define ND 500
#define NDP 512               /* padded K/N for MFMA */
#define NTOK (NB * NT)
#define INV_SCALE 0.04472135954999579f   /* 1/sqrt(500) */

__device__ __forceinline__ float b2f(bf16 x) { return __bfloat162float(x); }

/* =====================================================================
 * MFMA core: 128x128 block tile, 4 waves (2x2), each wave 4x4 of 16x16
 * A[128][32] from Ab (row-major, lda elems), B^T-style operand from Bb:
 * row n of Bb = column n of B, k-contiguous. nsteps K-steps of 32.
 * Fragment layouts (guide-verified): A[m=lane&15][k=8*(lane>>4)+j],
 * B[n=lane&15][k=...] symmetric, C col=lane&15, row=4*(lane>>4)+reg.
 * ===================================================================== */
__device__ __forceinline__ void mfma_core(const bf16* __restrict__ Ab, int lda,
                                          const bf16* __restrict__ Bb, int ldb,
                                          int nsteps, short* As, short* Bs,
                                          f32x4 (&acc)[4][4]) {
    const int tid = threadIdx.x;
    const int lane = tid & 63;
    const int wave = tid >> 6;
    const int wx = wave & 1, wy = wave >> 1;
    const int m16 = lane & 15, quad = lane >> 4;
    const int row = tid >> 2, seg = tid & 3;
    const bf16* a0 = Ab + (size_t)row * lda + seg * 8;
    const bf16* a1 = a0 + (size_t)64 * lda;
    const bf16* b0 = Bb + (size_t)row * ldb + seg * 8;
    const bf16* b1 = b0 + (size_t)64 * ldb;
    short* asd0 = As + row * 32 + seg * 8;
    short* asd1 = asd0 + 64 * 32;
    short* bsd0 = Bs + row * 32 + seg * 8;
    short* bsd1 = bsd0 + 64 * 32;
    for (int ks = 0; ks < nsteps; ks++) {
        const int ko = ks * 32;
        *(short8*)asd0 = *(const short8*)(a0 + ko);
        *(short8*)asd1 = *(const short8*)(a1 + ko);
        *(short8*)bsd0 = *(const short8*)(b0 + ko);
        *(short8*)bsd1 = *(const short8*)(b1 + ko);
        __syncthreads();
        short8 af[4], bfv[4];
        #pragma unroll
        for (int i = 0; i < 4; i++)
            af[i] = *(const short8*)&As[(wy * 64 + i * 16 + m16) * 32 + quad * 8];
        #pragma unroll
        for (int j = 0; j < 4; j++)
            bfv[j] = *(const short8*)&Bs[(wx * 64 + j * 16 + m16) * 32 + quad * 8];
        #pragma unroll
        for (int i = 0; i < 4; i++)
            #pragma unroll
            for (int j = 0; j < 4; j++)
                acc[i][j] = __builtin_amdgcn_mfma_f32_16x16x32_bf16(af[i], bfv[j], acc[i][j], 0, 0, 0);
        __syncthreads();
    }
}

/* ---- W (500x500 fp32, [k][n]) -> Wt (512x512 bf16, [n][k], zero-padded) ---- */
__global__ void transpose_w(const float* __restrict__ W, bf16* __restrict__ Wt) {
    __shared__ float t[32][33];
    int n0 = blockIdx.x * 32, k0 = blockIdx.y * 32;
    int a = threadIdx.x & 31, bq = threadIdx.x >> 5;   /* 8 rows per pass */
    #pragma unroll
    for (int it = 0; it < 4; it++) {
        int k = k0 + bq + it * 8, n = n0 + a;
        t[bq + it * 8][a] = (k < ND && n < ND) ? W[k * ND + n] : 0.f;
    }
    __syncthreads();
    #pragma unroll
    for (int it = 0; it < 4; it++) {
        int n = n0 + bq + it * 8;
        Wt[(size_t)n * NDP + k0 + a] = __float2bfloat16(t[a][bq + it * 8]);
    }
}

/* ---- K1: build g (B,T,512) bf16, zero-padded cols >= 500 ---- */
__global__ void build_g(const int* __restrict__ words, const int* __restrict__ pos,
                        const int* __restrict__ ner, const int* __restrict__ chunks,
                        const int* __restrict__ subj_pos, const int* __restrict__ obj_pos,
                        const int* __restrict__ on_path, const float* __restrict__ dep_feat,
                        const float* __restrict__ emb_w, const float* __restrict__ pos_w,
                        const float* __restrict__ ner_w, const float* __restrict__ chunk_w,
                        const float* __restrict__ position_w, bf16* __restrict__ g) {
    int tok = blockIdx.x;
    int w = words[tok], p = pos[tok], n = ner[tok], ck = chunks[tok];
    int sp = subj_pos[tok], op = obj_pos[tok], onp = on_path[tok];
    bf16* gr = g + (size_t)tok * NDP;
    for (int d = threadIdx.x; d < NDP; d += blockDim.x) {
        float v;
        if      (d < 300) v = emb_w[(size_t)w * 300 + d];
        else if (d < 335) v = pos_w[p * 35 + (d - 300)];
        else if (d < 365) v = ner_w[n * 30 + (d - 335)];
        else if (d < 395) v = chunk_w[ck * 30 + (d - 365)];
        else if (d < 425) v = position_w[sp * 30 + (d - 395)];
        else if (d < 455) v = position_w[op * 30 + (d - 425)];
        else if (d == 455) v = (float)onp;
        else if (d < 500) v = dep_feat[(size_t)tok * 44 + (d - 456)];
        else              v = 0.f;
        gr[d] = __float2bfloat16(v);
    }
}

/* ---- K2: subj max pool, grid (NB,4) x 128 ---- */
__global__ void subj_pool(const bf16* __restrict__ g, const int* __restrict__ subj_pos,
                          float* __restrict__ subj) {
    int b = blockIdx.x;
    int d = blockIdx.y * 128 + threadIdx.x;
    const bf16* gb = g + (size_t)b * NT * NDP + d;
    const int* sp = subj_pos + b * NT;
    float acc = -INFINITY;
    for (int t = 0; t < NT; t++) {
        float v = (sp[t] != 0) ? -1e12f : b2f(gb[(size_t)t * NDP]);
        acc = fmaxf(acc, v);
    }
    if (d < ND) subj[b * ND + d] = acc;
}

/* ---- K3: q = relu(so @ Wq + bq) ---- */
__global__ void compute_q(const float* __restrict__ subj, const float* __restrict__ Wq,
                          const float* __restrict__ bq, float* __restrict__ q) {
    int b = blockIdx.x, d = threadIdx.x;
    if (d >= ND) return;
    float acc = bq[d];
    for (int j = 0; j < ND; j++) {
        float s = subj[b * ND + j];
        acc += s * (Wq[(size_t)j * ND + d] + Wq[(size_t)(j + ND) * ND + d]);
    }
    q[b * ND + d] = fmaxf(acc, 0.f);
}

/* ---- K4: t = relu(q @ Wc[:500] + bc); w2 = t * Wk ---- */
__global__ void compute_t_w2(const float* __restrict__ q, const float* __restrict__ Wc,
                             const float* __restrict__ bc, const float* __restrict__ Wk,
                             float* __restrict__ w2) {
    int b = blockIdx.x, d = threadIdx.x;
    if (d >= ND) return;
    float acc = bc[d];
    for (int j = 0; j < ND; j++)
        acc += q[b * ND + j] * Wc[(size_t)j * ND + d];
    w2[b * ND + d] = fmaxf(acc, 0.f) * Wk[d];
}

/* ---- K5: k_logits ---- */
__global__ void compute_klog(const bf16* __restrict__ g, const float* __restrict__ w2,
                             const float* __restrict__ Wk_b, float* __restrict__ klog) {
    int tok = blockIdx.x;
    int b = tok >> 10;
    int lane = threadIdx.x;
    const bf16* gr = g + (size_t)tok * NDP;
    const float* wr = w2 + b * ND;
    float acc = 0.f;
    for (int d = lane; d < ND; d += 64) acc += b2f(gr[d]) * wr[d];
    #pragma unroll
    for (int off = 32; off; off >>= 1) acc += __shfl_down(acc, off, 64);
    if (lane == 0) klog[tok] = acc + Wk_b[0];
}

/* ---- K6a: softmax over T ---- */
__global__ void softmax_k(const float* __restrict__ klog, float* __restrict__ k) {
    int b = blockIdx.x, tid = threadIdx.x;
    __shared__ float red[256];
    float m = -INFINITY;
    for (int t = tid; t < NT; t += 256) m = fmaxf(m, klog[b * NT + t]);
    red[tid] = m; __syncthreads();
    for (int s = 128; s; s >>= 1) { if (tid < s) red[tid] = fmaxf(red[tid], red[tid + s]); __syncthreads(); }
    m = red[0]; __syncthreads();
    float sum = 0.f;
    for (int t = tid; t < NT; t += 256) sum += expf(klog[b * NT + t] - m);
    red[tid] = sum; __syncthreads();
    for (int s = 128; s; s >>= 1) { if (tid < s) red[tid] += red[tid + s]; __syncthreads(); }
    float inv = 1.f / red[0];
    for (int t = tid; t < NT; t += 256) k[b * NT + t] = expf(klog[b * NT + t] - m) * inv;
}

/* ---- K6b: c = sum_t k*g, grid (NB,4) x 128 ---- */
__global__ void compute_c(const bf16* __restrict__ g, const float* __restrict__ k,
                          float* __restrict__ c) {
    int b = blockIdx.x;
    int d = blockIdx.y * 128 + threadIdx.x;
    const bf16* gb = g + (size_t)b * NT * NDP + d;
    const float* kb = k + b * NT;
    float acc = 0.f;
    for (int t = 0; t < NT; t++)
        acc += kb[t] * b2f(gb[(size_t)t * NDP]);
    if (d < ND) c[b * ND + d] = acc;
}

/* ---- K7: m = relu([c,subj,subj] @ Wm + bm) ---- */
__global__ void compute_m(const float* __restrict__ c, const float* __restrict__ subj,
                          const float* __restrict__ Wm, const float* __restrict__ bm,
                          float* __restrict__ mvec) {
    int b = blockIdx.x, d = threadIdx.x;
    if (d >= ND) return;
    float acc = bm[d];
    for (int j = 0; j < ND; j++) {
        acc += c[b * ND + j] * Wm[(size_t)j * ND + d];
        acc += subj[b * ND + j] * (Wm[(size_t)(ND + j) * ND + d] + Wm[(size_t)(2 * ND + j) * ND + d]);
    }
    mvec[b * ND + d] = fmaxf(acc, 0.f);
}

/* ---- MFMA projection: C(NTOK,512) = g @ Wt^T + bias; mode 0: bf16 [t][512];
       mode 1: transposed bf16 store Vt[b*512 + c][s] ---- */
__global__ __launch_bounds__(256) void mfma_proj(const bf16* __restrict__ g, const bf16* __restrict__ Wt,
                                                 const float* __restrict__ bias, bf16* __restrict__ out0,
                                                 bf16* __restrict__ outT, int mode) {
    __shared__ short As[4096], Bs[4096];
    f32x4 acc[4][4] = {};
    int row0 = blockIdx.x * 128, col0 = blockIdx.y * 128;
    mfma_core(g + (size_t)row0 * NDP, NDP, Wt + (size_t)col0 * NDP, NDP, NDP / 32, As, Bs, acc);
    const int tid = threadIdx.x, lane = tid & 63, wave = tid >> 6;
    const int wx = wave & 1, wy = wave >> 1, m16 = lane & 15, quad = lane >> 4;
    #pragma unroll
    for (int j = 0; j < 4; j++) {
        int cg = col0 + wx * 64 + j * 16 + m16;
        float bv = (cg < ND) ? bias[cg] : 0.f;
        #pragma unroll
        for (int i = 0; i < 4; i++) {
            #pragma unroll
            for (int reg = 0; reg < 4; reg++) {
                int r = row0 + wy * 64 + i * 16 + quad * 4 + reg;
                float v = (cg < ND) ? (acc[i][j][reg] + bv) : 0.f;
                bf16 hv = __float2bfloat16(v);
                if (mode == 0) {
                    out0[(size_t)r * NDP + cg] = hv;
                } else {
                    int b = r >> 10, s = r & 1023;
                    outT[((size_t)(b * NDP) + cg) * NT + s] = hv;
                }
            }
        }
    }
}

/* ---- MFMA S: S[z] = key[z] @ query[z]^T, fp32 out ---- */
__global__ __launch_bounds__(256) void mfma_S(const bf16* __restrict__ key, const bf16* __restrict__ query,
                                              float* __restrict__ S) {
    __shared__ short As[4096], Bs[4096];
    f32x4 acc[4][4] = {};
    int z = blockIdx.z;
    int row0 = blockIdx.x * 128, col0 = blockIdx.y * 128;
    const bf16* kb = key + (size_t)z * NT * NDP;
    const bf16* qb = query + (size_t)z * NT * NDP;
    mfma_core(kb + (size_t)row0 * NDP, NDP, qb + (size_t)col0 * NDP, NDP, NDP / 32, As, Bs, acc);
    float* Sb = S + ((size_t)z << 20);
    const int tid = threadIdx.x, lane = tid & 63, wave = tid >> 6;
    const int wx = wave & 1, wy = wave >> 1, m16 = lane & 15, quad = lane >> 4;
    #pragma unroll
    for (int i = 0; i < 4; i++)
        #pragma unroll
        for (int reg = 0; reg < 4; reg++) {
            size_t r = row0 + wy * 64 + i * 16 + quad * 4 + reg;
            #pragma unroll
            for (int j = 0; j < 4; j++) {
                int c = col0 + wx * 64 + j * 16 + m16;
                Sb[(r << 10) + c] = acc[i][j][reg];
            }
        }
}

/* ---- double softmax per row; att fp32; write P2 bf16 in-place (row head) ---- */
__global__ void attn_rows(float* __restrict__ S, float* __restrict__ att_out) {
    int z = blockIdx.x >> 10, t = blockIdx.x & 1023;
    float* row = S + ((size_t)blockIdx.x << 10);
    int tid = threadIdx.x;   /* 256 */
    __shared__ float red[256];
    __shared__ float diag;
    float v[4];
    #pragma unroll
    for (int i = 0; i < 4; i++) v[i] = row[i * 256 + tid];
    float m = fmaxf(fmaxf(v[0], v[1]), fmaxf(v[2], v[3]));
    red[tid] = m; __syncthreads();
    for (int s = 128; s; s >>= 1) { if (tid < s) red[tid] = fmaxf(red[tid], red[tid + s]); __syncthreads(); }
    m = red[0]; __syncthreads();
    float e1[4], e2[4], s1 = 0.f, s2 = 0.f;
    #pragma unroll
    for (int i = 0; i < 4; i++) {
        e1[i] = expf(v[i] - m);
        e2[i] = expf((v[i] - m) * INV_SCALE);
        s1 += e1[i]; s2 += e2[i];
        if (i * 256 + tid == t) diag = e1[i];
    }
    red[tid] = s1; __syncthreads();
    for (int s = 128; s; s >>= 1) { if (tid < s) red[tid] += red[tid + s]; __syncthreads(); }
    s1 = red[0]; __syncthreads();
    red[tid] = s2; __syncthreads();
    for (int s = 128; s; s >>= 1) { if (tid < s) red[tid] += red[tid + s]; __syncthreads(); }
    s2 = red[0]; __syncthreads();
    if (tid == 0) att_out[(size_t)z * NT + t] = (1.f - diag / s1) * INV_SCALE;
    float inv2 = 1.f / s2;
    bf16* rowb = (bf16*)row;
    #pragma unroll
    for (int i = 0; i < 4; i++) rowb[i * 256 + tid] = __float2bfloat16(e2[i] * inv2);
}

/* ---- MFMA PV: out[z] = P2[z] @ V[z] * mvec, fp32 out (stride 500) ---- */
__global__ __launch_bounds__(256) void mfma_PV(const float* __restrict__ S, const bf16* __restrict__ valueT,
                                               const float* __restrict__ mvec, float* __restrict__ outp) {
    __shared__ short As[4096], Bs[4096];
    f32x4 acc[4][4] = {};
    int z = blockIdx.z;
    int row0 = blockIdx.x * 128, col0 = blockIdx.y * 128;
    const bf16* P2 = (const bf16*)(S + ((size_t)z << 20));   /* lda 2048 */
    const bf16* Vt = valueT + (size_t)z * NDP * NT;          /* ldb 1024 */
    mfma_core(P2 + (size_t)row0 * 2048, 2048, Vt + (size_t)col0 * NT, NT, NT / 32, As, Bs, acc);
    const int tid = threadIdx.x, lane = tid & 63, wave = tid >> 6;
    const int wx = wave & 1, wy = wave >> 1, m16 = lane & 15, quad = lane >> 4;
    #pragma unroll
    for (int j = 0; j < 4; j++) {
        int c = col0 + wx * 64 + j * 16 + m16;
        if (c >= ND) continue;
        float mm = mvec[z * ND + c];
        #pragma unroll
        for (int i = 0; i < 4; i++) {
            #pragma unroll
            for (int reg = 0; reg < 4; reg++) {
                int r = row0 + wy * 64 + i * 16 + quad * 4 + reg;
                outp[((size_t)(z * NT + r)) * ND + c] = acc[i][j][reg] * mm;
            }
        }
    }
}

extern "C" void kernel_launch(void* const* d_in, const int* in_sizes, int n_in,
                              void* d_out, int out_size, void* d_ws, size_t ws_size,
                              hipStream_t stream) {
    const int*   words     = (const int*)d_in[0];
    const int*   pos       = (const int*)d_in[2];
    const int*   ner       = (const int*)d_in[3];
    const int*   subj_pos  = (const int*)d_in[4];
    const int*   obj_pos   = (const int*)d_in[5];
    const int*   chunks    = (const int*)d_in[6];
    const int*   on_path   = (const int*)d_in[7];
    const float* dep_feat  = (const float*)d_in[8];
    const float* emb_w     = (const float*)d_in[9];
    const float* pos_w     = (const float*)d_in[10];
    const float* ner_w     = (const float*)d_in[11];
    const float* chunk_w   = (const float*)d_in[12];
    const float* position_w= (const float*)d_in[13];
    const float* Wq_w      = (const float*)d_in[14];
    const float* Wq_b      = (const float*)d_in[15];
    const float* Wc_w      = (const float*)d_in[16];
    const float* Wc_b      = (const float*)d_in[17];
    const float* Wk_w      = (const float*)d_in[18];
    const float* Wk_b      = (const float*)d_in[19];
    const float* Wm_w      = (const float*)d_in[20];
    const float* Wm_b      = (const float*)d_in[21];
    const float* K_w       = (const float*)d_in[22];
    const float* K_b       = (const float*)d_in[23];
    const float* Q_w       = (const float*)d_in[24];
    const float* Q_b       = (const float*)d_in[25];
    const float* V_w       = (const float*)d_in[26];
    const float* V_b       = (const float*)d_in[27];

    float* out_main = (float*)d_out;                       /* (B,T,500) fp32 */
    float* out_att  = out_main + (size_t)NTOK * ND;        /* (B,T) fp32 */

    /* ---- ws layout (~136 MB) ---- */
    char* wp = (char*)d_ws;
    float* subj = (float*)wp; wp += (size_t)NB * ND * 4;
    float* qb   = (float*)wp; wp += (size_t)NB * ND * 4;
    float* w2   = (float*)wp; wp += (size_t)NB * ND * 4;
    float* cb   = (float*)wp; wp += (size_t)NB * ND * 4;
    float* mv   = (float*)wp; wp += (size_t)NB * ND * 4;
    float* klog = (float*)wp; wp += (size_t)NB * NT * 4;
    float* kbuf = (float*)wp; wp += (size_t)NB * NT * 4;
    bf16* g     = (bf16*)wp;  wp += (size_t)NTOK * NDP * 2;
    bf16* Wt_k  = (bf16*)wp;  wp += (size_t)NDP * NDP * 2;
    bf16* Wt_q  = (bf16*)wp;  wp += (size_t)NDP * NDP * 2;
    bf16* Wt_v  = (bf16*)wp;  wp += (size_t)NDP * NDP * 2;
    bf16* key   = (bf16*)wp;  wp += (size_t)NTOK * NDP * 2;
    bf16* query = (bf16*)wp;  wp += (size_t)NTOK * NDP * 2;
    bf16* valT  = (bf16*)wp;  wp += (size_t)NTOK * NDP * 2;
    float* S    = (float*)wp; /* NB * 1M fp32 = 67 MB; P2 aliased into row heads */

    /* weight transposes (bf16, [n][k], 512x512 zero-padded) */
    dim3 gtw(16, 16);
    transpose_w<<<gtw, 256, 0, stream>>>(K_w, Wt_k);
    transpose_w<<<gtw, 256, 0, stream>>>(Q_w, Wt_q);
    transpose_w<<<gtw, 256, 0, stream>>>(V_w, Wt_v);

    /* phase A */
    build_g<<<NTOK, 128, 0, stream>>>(words, pos, ner, chunks, subj_pos, obj_pos,
                                      on_path, dep_feat, emb_w, pos_w, ner_w,
                                      chunk_w, position_w, g);
    subj_pool<<<dim3(NB, 4), 128, 0, stream>>>(g, subj_pos, subj);
    compute_q<<<NB, 512, 0, stream>>>(subj, Wq_w, Wq_b, qb);
    compute_t_w2<<<NB, 512, 0, stream>>>(qb, Wc_w, Wc_b, Wk_w, w2);
    compute_klog<<<NTOK, 64, 0, stream>>>(g, w2, Wk_b, klog);
    softmax_k<<<NB, 256, 0, stream>>>(klog, kbuf);
    compute_c<<<dim3(NB, 4), 128, 0, stream>>>(g, kbuf, cb);
    compute_m<<<NB, 512, 0, stream>>>(cb, subj, Wm_w, Wm_b, mv);

    /* phase B: MFMA GEMMs */
    dim3 gproj(NTOK / 128, NDP / 128);
    mfma_proj<<<gproj, 256, 0, stream>>>(g, Wt_k, K_b, key,  nullptr, 0);
    mfma_proj<<<gproj, 256, 0, stream>>>(g, Wt_q, Q_b, query, nullptr, 0);
    mfma_proj<<<gproj, 256, 0, stream>>>(g, Wt_v, V_b, nullptr, valT, 1);

    dim3 gS(NT / 128, NT / 128, NB);
    mfma_S<<<gS, 256, 0, stream>>>(key, query, S);

    attn_rows<<<NTOK, 256, 0, stream>>>(S, out_att);

    dim3 gPV(NT / 128, NDP / 128, NB);
    mfma_PV<<<gPV, 256, 0, stream>>>(S, valT, mv, out_main);

    (void)in_sizes; (void)n_in; (void)out_size; (void)ws_size;
}

// Round 7
// 496.937 us; speedup vs baseline: 3.6298x; 1.1965x over previous
//
#include <hip/hip_runtime.h>
#include <hip/hip_bf16.h>

typedef __hip_bfloat16 bf16;
typedef __attribute__((ext_vector_type(8))) short short8;
typedef __attribute__((ext_vector_type(4))) float f32x4;

#define NB 16
#define NT 1024
#define ND 500
#define NDP 512               /* padded K/N for MFMA */
#define NTOK (NB * NT)
#define JS 8                  /* j/t split factor for phase-A kernels */
#define INV_SCALE 0.04472135954999579f   /* 1/sqrt(500) */

__device__ __forceinline__ float b2f(bf16 x) { return __bfloat162float(x); }

/* =====================================================================
 * MFMA core: 128x128 block tile, 4 waves (2x2), each wave 4x4 of 16x16
 * ===================================================================== */
__device__ __forceinline__ void mfma_core(const bf16* __restrict__ Ab, int lda,
                                          const bf16* __restrict__ Bb, int ldb,
                                          int nsteps, short* As, short* Bs,
                                          f32x4 (&acc)[4][4]) {
    const int tid = threadIdx.x;
    const int lane = tid & 63;
    const int wave = tid >> 6;
    const int wx = wave & 1, wy = wave >> 1;
    const int m16 = lane & 15, quad = lane >> 4;
    const int row = tid >> 2, seg = tid & 3;
    const bf16* a0 = Ab + (size_t)row * lda + seg * 8;
    const bf16* a1 = a0 + (size_t)64 * lda;
    const bf16* b0 = Bb + (size_t)row * ldb + seg * 8;
    const bf16* b1 = b0 + (size_t)64 * ldb;
    short* asd0 = As + row * 32 + seg * 8;
    short* asd1 = asd0 + 64 * 32;
    short* bsd0 = Bs + row * 32 + seg * 8;
    short* bsd1 = bsd0 + 64 * 32;
    for (int ks = 0; ks < nsteps; ks++) {
        const int ko = ks * 32;
        *(short8*)asd0 = *(const short8*)(a0 + ko);
        *(short8*)asd1 = *(const short8*)(a1 + ko);
        *(short8*)bsd0 = *(const short8*)(b0 + ko);
        *(short8*)bsd1 = *(const short8*)(b1 + ko);
        __syncthreads();
        short8 af[4], bfv[4];
        #pragma unroll
        for (int i = 0; i < 4; i++)
            af[i] = *(const short8*)&As[(wy * 64 + i * 16 + m16) * 32 + quad * 8];
        #pragma unroll
        for (int j = 0; j < 4; j++)
            bfv[j] = *(const short8*)&Bs[(wx * 64 + j * 16 + m16) * 32 + quad * 8];
        #pragma unroll
        for (int i = 0; i < 4; i++)
            #pragma unroll
            for (int j = 0; j < 4; j++)
                acc[i][j] = __builtin_amdgcn_mfma_f32_16x16x32_bf16(af[i], bfv[j], acc[i][j], 0, 0, 0);
        __syncthreads();
    }
}

/* ---- W (500x500 fp32 [k][n]) -> Wt (512x512 bf16 [n][k]); z selects K/Q/V ---- */
__global__ void transpose_w3(const float* __restrict__ WK, const float* __restrict__ WQ,
                             const float* __restrict__ WV, bf16* __restrict__ WtK,
                             bf16* __restrict__ WtQ, bf16* __restrict__ WtV) {
    const float* W = (blockIdx.z == 0) ? WK : (blockIdx.z == 1) ? WQ : WV;
    bf16* Wt = (blockIdx.z == 0) ? WtK : (blockIdx.z == 1) ? WtQ : WtV;
    __shared__ float t[32][33];
    int n0 = blockIdx.x * 32, k0 = blockIdx.y * 32;
    int a = threadIdx.x & 31, bq = threadIdx.x >> 5;
    #pragma unroll
    for (int it = 0; it < 4; it++) {
        int k = k0 + bq + it * 8, n = n0 + a;
        t[bq + it * 8][a] = (k < ND && n < ND) ? W[k * ND + n] : 0.f;
    }
    __syncthreads();
    #pragma unroll
    for (int it = 0; it < 4; it++) {
        int n = n0 + bq + it * 8;
        Wt[(size_t)n * NDP + k0 + a] = __float2bfloat16(t[a][bq + it * 8]);
    }
}

/* ---- K1: build g (B,T,512) bf16, zero-padded cols >= 500 ---- */
__global__ void build_g(const int* __restrict__ words, const int* __restrict__ pos,
                        const int* __restrict__ ner, const int* __restrict__ chunks,
                        const int* __restrict__ subj_pos, const int* __restrict__ obj_pos,
                        const int* __restrict__ on_path, const float* __restrict__ dep_feat,
                        const float* __restrict__ emb_w, const float* __restrict__ pos_w,
                        const float* __restrict__ ner_w, const float* __restrict__ chunk_w,
                        const float* __restrict__ position_w, bf16* __restrict__ g) {
    int tok = blockIdx.x;
    int w = words[tok], p = pos[tok], n = ner[tok], ck = chunks[tok];
    int sp = subj_pos[tok], op = obj_pos[tok], onp = on_path[tok];
    bf16* gr = g + (size_t)tok * NDP;
    for (int d = threadIdx.x; d < NDP; d += blockDim.x) {
        float v;
        if      (d < 300) v = emb_w[(size_t)w * 300 + d];
        else if (d < 335) v = pos_w[p * 35 + (d - 300)];
        else if (d < 365) v = ner_w[n * 30 + (d - 335)];
        else if (d < 395) v = chunk_w[ck * 30 + (d - 365)];
        else if (d < 425) v = position_w[sp * 30 + (d - 395)];
        else if (d < 455) v = position_w[op * 30 + (d - 425)];
        else if (d == 455) v = (float)onp;
        else if (d < 500) v = dep_feat[(size_t)tok * 44 + (d - 456)];
        else              v = 0.f;
        gr[d] = __float2bfloat16(v);
    }
}

/* ---- subj max pool, split over t: grid (NB, JS) x 64, short8 loads ---- */
__global__ void pool_part(const bf16* __restrict__ g, const int* __restrict__ subj_pos,
                          float* __restrict__ part) {
    int b = blockIdx.x, s = blockIdx.y;
    int c0 = threadIdx.x * 8;                        /* 64 threads x 8 = 512 cols */
    const bf16* gb = g + (size_t)b * NT * NDP + c0;
    const int* sp = subj_pos + b * NT;
    float mx[8];
    #pragma unroll
    for (int i = 0; i < 8; i++) mx[i] = -INFINITY;
    int t0 = s * (NT / JS), t1 = t0 + (NT / JS);
    for (int t = t0; t < t1; t++) {
        int masked = (sp[t] != 0);
        short8 v8 = *(const short8*)(gb + (size_t)t * NDP);
        #pragma unroll
        for (int i = 0; i < 8; i++) {
            float v = masked ? -1e12f : b2f(((bf16*)&v8)[i]);
            mx[i] = fmaxf(mx[i], v);
        }
    }
    float* pr = part + ((size_t)(b * JS + s)) * NDP + c0;
    #pragma unroll
    for (int i = 0; i < 8; i++) pr[i] = mx[i];
}

__global__ void pool_reduce(const float* __restrict__ part, float* __restrict__ subj) {
    int b = blockIdx.x, d = threadIdx.x;   /* 512 */
    float mx = -INFINITY;
    #pragma unroll
    for (int s = 0; s < JS; s++) mx = fmaxf(mx, part[((size_t)(b * JS + s)) * NDP + d]);
    if (d < ND) subj[b * ND + d] = mx;
}

/* ---- c = sum_t k*g, split over t ---- */
__global__ void c_part(const bf16* __restrict__ g, const float* __restrict__ k,
                       float* __restrict__ part) {
    int b = blockIdx.x, s = blockIdx.y;
    int c0 = threadIdx.x * 8;
    const bf16* gb = g + (size_t)b * NT * NDP + c0;
    const float* kb = k + b * NT;
    float acc[8] = {};
    int t0 = s * (NT / JS), t1 = t0 + (NT / JS);
    for (int t = t0; t < t1; t++) {
        float kv = kb[t];
        short8 v8 = *(const short8*)(gb + (size_t)t * NDP);
        #pragma unroll
        for (int i = 0; i < 8; i++) acc[i] += kv * b2f(((bf16*)&v8)[i]);
    }
    float* pr = part + ((size_t)(b * JS + s)) * NDP + c0;
    #pragma unroll
    for (int i = 0; i < 8; i++) pr[i] = acc[i];
}

__global__ void c_reduce(const float* __restrict__ part, float* __restrict__ c) {
    int b = blockIdx.x, d = threadIdx.x;
    float acc = 0.f;
    #pragma unroll
    for (int s = 0; s < JS; s++) acc += part[((size_t)(b * JS + s)) * NDP + d];
    if (d < ND) c[b * ND + d] = acc;
}

/* ---- GEMV partials: mode 0 q, 1 t, 2 m. grid (NB, JS) x 512 ---- */
__global__ void gemv_part(const float* __restrict__ x1, const float* __restrict__ x2,
                          const float* __restrict__ W, float* __restrict__ part, int mode) {
    int b = blockIdx.x, s = blockIdx.y, d = threadIdx.x;
    int j0 = s * 63, j1 = min(ND, j0 + 63);
    float acc = 0.f;
    if (d < ND) {
        if (mode == 0) {
            for (int j = j0; j < j1; j++)
                acc += x1[b * ND + j] * (W[(size_t)j * ND + d] + W[(size_t)(j + ND) * ND + d]);
        } else if (mode == 1) {
            for (int j = j0; j < j1; j++)
                acc += x1[b * ND + j] * W[(size_t)j * ND + d];
        } else {
            for (int j = j0; j < j1; j++) {
                acc += x1[b * ND + j] * W[(size_t)j * ND + d];
                acc += x2[b * ND + j] * (W[(size_t)(ND + j) * ND + d] + W[(size_t)(2 * ND + j) * ND + d]);
            }
        }
    }
    part[((size_t)(b * JS + s)) * NDP + d] = acc;
}

/* ---- reduce + bias + relu (+ optional *Wk) ---- */
__global__ void gemv_reduce(const float* __restrict__ part, const float* __restrict__ bias,
                            const float* __restrict__ Wk, float* __restrict__ out) {
    int b = blockIdx.x, d = threadIdx.x;
    if (d >= ND) return;
    float acc = bias[d];
    #pragma unroll
    for (int s = 0; s < JS; s++) acc += part[((size_t)(b * JS + s)) * NDP + d];
    acc = fmaxf(acc, 0.f);
    if (Wk) acc *= Wk[d];
    out[b * ND + d] = acc;
}

/* ---- klog ---- */
__global__ void compute_klog(const bf16* __restrict__ g, const float* __restrict__ w2,
                             const float* __restrict__ Wk_b, float* __restrict__ klog) {
    int tok = blockIdx.x;
    int b = tok >> 10;
    int lane = threadIdx.x;
    const bf16* gr = g + (size_t)tok * NDP;
    const float* wr = w2 + b * ND;
    float acc = 0.f;
    for (int d = lane; d < ND; d += 64) acc += b2f(gr[d]) * wr[d];
    #pragma unroll
    for (int off = 32; off; off >>= 1) acc += __shfl_down(acc, off, 64);
    if (lane == 0) klog[tok] = acc + Wk_b[0];
}

/* ---- softmax over T ---- */
__global__ void softmax_k(const float* __restrict__ klog, float* __restrict__ k) {
    int b = blockIdx.x, tid = threadIdx.x;
    __shared__ float red[256];
    float m = -INFINITY;
    for (int t = tid; t < NT; t += 256) m = fmaxf(m, klog[b * NT + t]);
    red[tid] = m; __syncthreads();
    for (int s = 128; s; s >>= 1) { if (tid < s) red[tid] = fmaxf(red[tid], red[tid + s]); __syncthreads(); }
    m = red[0]; __syncthreads();
    float sum = 0.f;
    for (int t = tid; t < NT; t += 256) sum += expf(klog[b * NT + t] - m);
    red[tid] = sum; __syncthreads();
    for (int s = 128; s; s >>= 1) { if (tid < s) red[tid] += red[tid + s]; __syncthreads(); }
    float inv = 1.f / red[0];
    for (int t = tid; t < NT; t += 256) k[b * NT + t] = expf(klog[b * NT + t] - m) * inv;
}

/* ---- MFMA projection ---- */
__global__ __launch_bounds__(256) void mfma_proj(const bf16* __restrict__ g, const bf16* __restrict__ Wt,
                                                 const float* __restrict__ bias, bf16* __restrict__ out0,
                                                 bf16* __restrict__ outT, int mode) {
    __shared__ short As[4096], Bs[4096];
    f32x4 acc[4][4] = {};
    int row0 = blockIdx.x * 128, col0 = blockIdx.y * 128;
    mfma_core(g + (size_t)row0 * NDP, NDP, Wt + (size_t)col0 * NDP, NDP, NDP / 32, As, Bs, acc);
    const int tid = threadIdx.x, lane = tid & 63, wave = tid >> 6;
    const int wx = wave & 1, wy = wave >> 1, m16 = lane & 15, quad = lane >> 4;
    #pragma unroll
    for (int j = 0; j < 4; j++) {
        int cg = col0 + wx * 64 + j * 16 + m16;
        float bv = (cg < ND) ? bias[cg] : 0.f;
        #pragma unroll
        for (int i = 0; i < 4; i++) {
            #pragma unroll
            for (int reg = 0; reg < 4; reg++) {
                int r = row0 + wy * 64 + i * 16 + quad * 4 + reg;
                float v = (cg < ND) ? (acc[i][j][reg] + bv) : 0.f;
                bf16 hv = __float2bfloat16(v);
                if (mode == 0) {
                    out0[(size_t)r * NDP + cg] = hv;
                } else {
                    int b = r >> 10, s = r & 1023;
                    outT[((size_t)(b * NDP) + cg) * NT + s] = hv;
                }
            }
        }
    }
}

/* ---- MFMA S ---- */
__global__ __launch_bounds__(256) void mfma_S(const bf16* __restrict__ key, const bf16* __restrict__ query,
                                              float* __restrict__ S) {
    __shared__ short As[4096], Bs[4096];
    f32x4 acc[4][4] = {};
    int z = blockIdx.z;
    int row0 = blockIdx.x * 128, col0 = blockIdx.y * 128;
    const bf16* kb = key + (size_t)z * NT * NDP;
    const bf16* qb = query + (size_t)z * NT * NDP;
    mfma_core(kb + (size_t)row0 * NDP, NDP, qb + (size_t)col0 * NDP, NDP, NDP / 32, As, Bs, acc);
    float* Sb = S + ((size_t)z << 20);
    const int tid = threadIdx.x, lane = tid & 63, wave = tid >> 6;
    const int wx = wave & 1, wy = wave >> 1, m16 = lane & 15, quad = lane >> 4;
    #pragma unroll
    for (int i = 0; i < 4; i++)
        #pragma unroll
        for (int reg = 0; reg < 4; reg++) {
            size_t r = row0 + wy * 64 + i * 16 + quad * 4 + reg;
            #pragma unroll
            for (int j = 0; j < 4; j++) {
                int c = col0 + wx * 64 + j * 16 + m16;
                Sb[(r << 10) + c] = acc[i][j][reg];
            }
        }
}

/* ---- double softmax per row; att fp32; write P2 bf16 in-place (row head) ---- */
__global__ void attn_rows(float* __restrict__ S, float* __restrict__ att_out) {
    int z = blockIdx.x >> 10, t = blockIdx.x & 1023;
    float* row = S + ((size_t)blockIdx.x << 10);
    int tid = threadIdx.x;   /* 256 */
    __shared__ float red[256];
    __shared__ float diag;
    float v[4];
    #pragma unroll
    for (int i = 0; i < 4; i++) v[i] = row[i * 256 + tid];
    float m = fmaxf(fmaxf(v[0], v[1]), fmaxf(v[2], v[3]));
    red[tid] = m; __syncthreads();
    for (int s = 128; s; s >>= 1) { if (tid < s) red[tid] = fmaxf(red[tid], red[tid + s]); __syncthreads(); }
    m = red[0]; __syncthreads();
    float e1[4], e2[4], s1 = 0.f, s2 = 0.f;
    #pragma unroll
    for (int i = 0; i < 4; i++) {
        e1[i] = expf(v[i] - m);
        e2[i] = expf((v[i] - m) * INV_SCALE);
        s1 += e1[i]; s2 += e2[i];
        if (i * 256 + tid == t) diag = e1[i];
    }
    red[tid] = s1; __syncthreads();
    for (int s = 128; s; s >>= 1) { if (tid < s) red[tid] += red[tid + s]; __syncthreads(); }
    s1 = red[0]; __syncthreads();
    red[tid] = s2; __syncthreads();
    for (int s = 128; s; s >>= 1) { if (tid < s) red[tid] += red[tid + s]; __syncthreads(); }
    s2 = red[0]; __syncthreads();
    if (tid == 0) att_out[(size_t)z * NT + t] = (1.f - diag / s1) * INV_SCALE;
    float inv2 = 1.f / s2;
    bf16* rowb = (bf16*)row;
    #pragma unroll
    for (int i = 0; i < 4; i++) rowb[i * 256 + tid] = __float2bfloat16(e2[i] * inv2);
}

/* ---- MFMA PV ---- */
__global__ __launch_bounds__(256) void mfma_PV(const float* __restrict__ S, const bf16* __restrict__ valueT,
                                               const float* __restrict__ mvec, float* __restrict__ outp) {
    __shared__ short As[4096], Bs[4096];
    f32x4 acc[4][4] = {};
    int z = blockIdx.z;
    int row0 = blockIdx.x * 128, col0 = blockIdx.y * 128;
    const bf16* P2 = (const bf16*)(S + ((size_t)z << 20));   /* lda 2048 */
    const bf16* Vt = valueT + (size_t)z * NDP * NT;          /* ldb 1024 */
    mfma_core(P2 + (size_t)row0 * 2048, 2048, Vt + (size_t)col0 * NT, NT, NT / 32, As, Bs, acc);
    const int tid = threadIdx.x, lane = tid & 63, wave = tid >> 6;
    const int wx = wave & 1, wy = wave >> 1, m16 = lane & 15, quad = lane >> 4;
    #pragma unroll
    for (int j = 0; j < 4; j++) {
        int c = col0 + wx * 64 + j * 16 + m16;
        if (c >= ND) continue;
        float mm = mvec[z * ND + c];
        #pragma unroll
        for (int i = 0; i < 4; i++) {
            #pragma unroll
            for (int reg = 0; reg < 4; reg++) {
                int r = row0 + wy * 64 + i * 16 + quad * 4 + reg;
                outp[((size_t)(z * NT + r)) * ND + c] = acc[i][j][reg] * mm;
            }
        }
    }
}

extern "C" void kernel_launch(void* const* d_in, const int* in_sizes, int n_in,
                              void* d_out, int out_size, void* d_ws, size_t ws_size,
                              hipStream_t stream) {
    const int*   words     = (const int*)d_in[0];
    const int*   pos       = (const int*)d_in[2];
    const int*   ner       = (const int*)d_in[3];
    const int*   subj_pos  = (const int*)d_in[4];
    const int*   obj_pos   = (const int*)d_in[5];
    const int*   chunks    = (const int*)d_in[6];
    const int*   on_path   = (const int*)d_in[7];
    const float* dep_feat  = (const float*)d_in[8];
    const float* emb_w     = (const float*)d_in[9];
    const float* pos_w     = (const float*)d_in[10];
    const float* ner_w     = (const float*)d_in[11];
    const float* chunk_w   = (const float*)d_in[12];
    const float* position_w= (const float*)d_in[13];
    const float* Wq_w      = (const float*)d_in[14];
    const float* Wq_b      = (const float*)d_in[15];
    const float* Wc_w      = (const float*)d_in[16];
    const float* Wc_b      = (const float*)d_in[17];
    const float* Wk_w      = (const float*)d_in[18];
    const float* Wk_b      = (const float*)d_in[19];
    const float* Wm_w      = (const float*)d_in[20];
    const float* Wm_b      = (const float*)d_in[21];
    const float* K_w       = (const float*)d_in[22];
    const float* K_b       = (const float*)d_in[23];
    const float* Q_w       = (const float*)d_in[24];
    const float* Q_b       = (const float*)d_in[25];
    const float* V_w       = (const float*)d_in[26];
    const float* V_b       = (const float*)d_in[27];

    float* out_main = (float*)d_out;                       /* (B,T,500) fp32 */
    float* out_att  = out_main + (size_t)NTOK * ND;        /* (B,T) fp32 */

    /* ---- ws layout (~136.5 MB) ---- */
    char* wp = (char*)d_ws;
    float* subj = (float*)wp; wp += (size_t)NB * ND * 4;
    float* qb   = (float*)wp; wp += (size_t)NB * ND * 4;
    float* w2   = (float*)wp; wp += (size_t)NB * ND * 4;
    float* cb   = (float*)wp; wp += (size_t)NB * ND * 4;
    float* mv   = (float*)wp; wp += (size_t)NB * ND * 4;
    float* klog = (float*)wp; wp += (size_t)NB * NT * 4;
    float* kbuf = (float*)wp; wp += (size_t)NB * NT * 4;
    float* part = (float*)wp; wp += (size_t)NB * JS * NDP * 4;   /* shared partial buffer */
    bf16* g     = (bf16*)wp;  wp += (size_t)NTOK * NDP * 2;
    bf16* Wt_k  = (bf16*)wp;  wp += (size_t)NDP * NDP * 2;
    bf16* Wt_q  = (bf16*)wp;  wp += (size_t)NDP * NDP * 2;
    bf16* Wt_v  = (bf16*)wp;  wp += (size_t)NDP * NDP * 2;
    bf16* key   = (bf16*)wp;  wp += (size_t)NTOK * NDP * 2;
    bf16* query = (bf16*)wp;  wp += (size_t)NTOK * NDP * 2;
    bf16* valT  = (bf16*)wp;  wp += (size_t)NTOK * NDP * 2;
    float* S    = (float*)wp; /* NB * 1M fp32 = 67 MB; P2 aliased into row heads */

    transpose_w3<<<dim3(16, 16, 3), 256, 0, stream>>>(K_w, Q_w, V_w, Wt_k, Wt_q, Wt_v);

    /* phase A: g + split-reduction dense chain */
    build_g<<<NTOK, 128, 0, stream>>>(words, pos, ner, chunks, subj_pos, obj_pos,
                                      on_path, dep_feat, emb_w, pos_w, ner_w,
                                      chunk_w, position_w, g);
    pool_part<<<dim3(NB, JS), 64, 0, stream>>>(g, subj_pos, part);
    pool_reduce<<<NB, 512, 0, stream>>>(part, subj);
    gemv_part<<<dim3(NB, JS), 512, 0, stream>>>(subj, nullptr, Wq_w, part, 0);
    gemv_reduce<<<NB, 512, 0, stream>>>(part, Wq_b, nullptr, qb);
    gemv_part<<<dim3(NB, JS), 512, 0, stream>>>(qb, nullptr, Wc_w, part, 1);
    gemv_reduce<<<NB, 512, 0, stream>>>(part, Wc_b, Wk_w, w2);
    compute_klog<<<NTOK, 64, 0, stream>>>(g, w2, Wk_b, klog);
    softmax_k<<<NB, 256, 0, stream>>>(klog, kbuf);
    c_part<<<dim3(NB, JS), 64, 0, stream>>>(g, kbuf, part);
    c_reduce<<<NB, 512, 0, stream>>>(part, cb);
    gemv_part<<<dim3(NB, JS), 512, 0, stream>>>(cb, subj, Wm_w, part, 2);
    gemv_reduce<<<NB, 512, 0, stream>>>(part, Wm_b, nullptr, mv);

    /* phase B: MFMA GEMMs */
    dim3 gproj(NTOK / 128, NDP / 128);
    mfma_proj<<<gproj, 256, 0, stream>>>(g, Wt_k, K_b, key,  nullptr, 0);
    mfma_proj<<<gproj, 256, 0, stream>>>(g, Wt_q, Q_b, query, nullptr, 0);
    mfma_proj<<<gproj, 256, 0, stream>>>(g, Wt_v, V_b, nullptr, valT, 1);

    dim3 gS(NT / 128, NT / 128, NB);
    mfma_S<<<gS, 256, 0, stream>>>(key, query, S);

    attn_rows<<<NTOK, 256, 0, stream>>>(S, out_att);

    dim3 gPV(NT / 128, NDP / 128, NB);
    mfma_PV<<<gPV, 256, 0, stream>>>(S, valT, mv, out_main);

    (void)in_sizes; (void)n_in; (void)out_size; (void)ws_size;
}

// Round 8
// 464.346 us; speedup vs baseline: 3.8846x; 1.0702x over previous
//
#include <hip/hip_runtime.h>
#include <hip/hip_bf16.h>

typedef __hip_bfloat16 bf16;
typedef __attribute__((ext_vector_type(8))) short short8;
typedef __attribute__((ext_vector_type(4))) float f32x4;

#define NB 16
#define NT 1024
#define ND 500
#define NDP 512               /* padded K/N for MFMA */
#define NTOK (NB * NT)
#define JS 8                  /* j/t split factor for phase-A kernels */
#define LSTR 40               /* LDS row stride in shorts (32 data + 8 pad) */
#define INV_SCALE 0.04472135954999579f   /* 1/sqrt(500) */

__device__ __forceinline__ float b2f(bf16 x) { return __bfloat162float(x); }

/* =====================================================================
 * MFMA core: 128x128 block tile, 4 waves (2x2), each wave 4x4 of 16x16.
 * LDS rows padded to LSTR=40 shorts: conflict-free ds_read_b128 within
 * 16-lane phases (stride-32 had 4-way conflicts -> 2.1M SQ_LDS_BANK_CONFLICT).
 * ===================================================================== */
__device__ __forceinline__ void mfma_core(const bf16* __restrict__ Ab, int lda,
                                          const bf16* __restrict__ Bb, int ldb,
                                          int nsteps, short* As, short* Bs,
                                          f32x4 (&acc)[4][4]) {
    const int tid = threadIdx.x;
    const int lane = tid & 63;
    const int wave = tid >> 6;
    const int wx = wave & 1, wy = wave >> 1;
    const int m16 = lane & 15, quad = lane >> 4;
    const int row = tid >> 2, seg = tid & 3;
    const bf16* a0 = Ab + (size_t)row * lda + seg * 8;
    const bf16* a1 = a0 + (size_t)64 * lda;
    const bf16* b0 = Bb + (size_t)row * ldb + seg * 8;
    const bf16* b1 = b0 + (size_t)64 * ldb;
    short* asd0 = As + row * LSTR + seg * 8;
    short* asd1 = asd0 + 64 * LSTR;
    short* bsd0 = Bs + row * LSTR + seg * 8;
    short* bsd1 = bsd0 + 64 * LSTR;
    for (int ks = 0; ks < nsteps; ks++) {
        const int ko = ks * 32;
        *(short8*)asd0 = *(const short8*)(a0 + ko);
        *(short8*)asd1 = *(const short8*)(a1 + ko);
        *(short8*)bsd0 = *(const short8*)(b0 + ko);
        *(short8*)bsd1 = *(const short8*)(b1 + ko);
        __syncthreads();
        short8 af[4], bfv[4];
        #pragma unroll
        for (int i = 0; i < 4; i++)
            af[i] = *(const short8*)&As[(wy * 64 + i * 16 + m16) * LSTR + quad * 8];
        #pragma unroll
        for (int j = 0; j < 4; j++)
            bfv[j] = *(const short8*)&Bs[(wx * 64 + j * 16 + m16) * LSTR + quad * 8];
        #pragma unroll
        for (int i = 0; i < 4; i++)
            #pragma unroll
            for (int j = 0; j < 4; j++)
                acc[i][j] = __builtin_amdgcn_mfma_f32_16x16x32_bf16(af[i], bfv[j], acc[i][j], 0, 0, 0);
        __syncthreads();
    }
}

/* ---- W (500x500 fp32 [k][n]) -> Wt (512x512 bf16 [n][k]); z selects K/Q/V ---- */
__global__ void transpose_w3(const float* __restrict__ WK, const float* __restrict__ WQ,
                             const float* __restrict__ WV, bf16* __restrict__ Wt_all) {
    const float* W = (blockIdx.z == 0) ? WK : (blockIdx.z == 1) ? WQ : WV;
    bf16* Wt = Wt_all + (size_t)blockIdx.z * NDP * NDP;
    __shared__ float t[32][33];
    int n0 = blockIdx.x * 32, k0 = blockIdx.y * 32;
    int a = threadIdx.x & 31, bq = threadIdx.x >> 5;
    #pragma unroll
    for (int it = 0; it < 4; it++) {
        int k = k0 + bq + it * 8, n = n0 + a;
        t[bq + it * 8][a] = (k < ND && n < ND) ? W[k * ND + n] : 0.f;
    }
    __syncthreads();
    #pragma unroll
    for (int it = 0; it < 4; it++) {
        int n = n0 + bq + it * 8;
        Wt[(size_t)n * NDP + k0 + a] = __float2bfloat16(t[a][bq + it * 8]);
    }
}

/* ---- build g (B,T,512) bf16, zero-padded cols >= 500 ---- */
__global__ void build_g(const int* __restrict__ words, const int* __restrict__ pos,
                        const int* __restrict__ ner, const int* __restrict__ chunks,
                        const int* __restrict__ subj_pos, const int* __restrict__ obj_pos,
                        const int* __restrict__ on_path, const float* __restrict__ dep_feat,
                        const float* __restrict__ emb_w, const float* __restrict__ pos_w,
                        const float* __restrict__ ner_w, const float* __restrict__ chunk_w,
                        const float* __restrict__ position_w, bf16* __restrict__ g) {
    int tok = blockIdx.x;
    int w = words[tok], p = pos[tok], n = ner[tok], ck = chunks[tok];
    int sp = subj_pos[tok], op = obj_pos[tok], onp = on_path[tok];
    bf16* gr = g + (size_t)tok * NDP;
    for (int d = threadIdx.x; d < NDP; d += blockDim.x) {
        float v;
        if      (d < 300) v = emb_w[(size_t)w * 300 + d];
        else if (d < 335) v = pos_w[p * 35 + (d - 300)];
        else if (d < 365) v = ner_w[n * 30 + (d - 335)];
        else if (d < 395) v = chunk_w[ck * 30 + (d - 365)];
        else if (d < 425) v = position_w[sp * 30 + (d - 395)];
        else if (d < 455) v = position_w[op * 30 + (d - 425)];
        else if (d == 455) v = (float)onp;
        else if (d < 500) v = dep_feat[(size_t)tok * 44 + (d - 456)];
        else              v = 0.f;
        gr[d] = __float2bfloat16(v);
    }
}

/* ---- subj max pool, split over t: grid (NB, JS) x 64, short8 loads ---- */
__global__ void pool_part(const bf16* __restrict__ g, const int* __restrict__ subj_pos,
                          float* __restrict__ part) {
    int b = blockIdx.x, s = blockIdx.y;
    int c0 = threadIdx.x * 8;
    const bf16* gb = g + (size_t)b * NT * NDP + c0;
    const int* sp = subj_pos + b * NT;
    float mx[8];
    #pragma unroll
    for (int i = 0; i < 8; i++) mx[i] = -INFINITY;
    int t0 = s * (NT / JS), t1 = t0 + (NT / JS);
    for (int t = t0; t < t1; t++) {
        int masked = (sp[t] != 0);
        short8 v8 = *(const short8*)(gb + (size_t)t * NDP);
        #pragma unroll
        for (int i = 0; i < 8; i++) {
            float v = masked ? -1e12f : b2f(((bf16*)&v8)[i]);
            mx[i] = fmaxf(mx[i], v);
        }
    }
    float* pr = part + ((size_t)(b * JS + s)) * NDP + c0;
    #pragma unroll
    for (int i = 0; i < 8; i++) pr[i] = mx[i];
}

__global__ void pool_reduce(const float* __restrict__ part, float* __restrict__ subj) {
    int b = blockIdx.x, d = threadIdx.x;
    float mx = -INFINITY;
    #pragma unroll
    for (int s = 0; s < JS; s++) mx = fmaxf(mx, part[((size_t)(b * JS + s)) * NDP + d]);
    if (d < ND) subj[b * ND + d] = mx;
}

/* ---- c = sum_t k*g, split over t ---- */
__global__ void c_part(const bf16* __restrict__ g, const float* __restrict__ k,
                       float* __restrict__ part) {
    int b = blockIdx.x, s = blockIdx.y;
    int c0 = threadIdx.x * 8;
    const bf16* gb = g + (size_t)b * NT * NDP + c0;
    const float* kb = k + b * NT;
    float acc[8] = {};
    int t0 = s * (NT / JS), t1 = t0 + (NT / JS);
    for (int t = t0; t < t1; t++) {
        float kv = kb[t];
        short8 v8 = *(const short8*)(gb + (size_t)t * NDP);
        #pragma unroll
        for (int i = 0; i < 8; i++) acc[i] += kv * b2f(((bf16*)&v8)[i]);
    }
    float* pr = part + ((size_t)(b * JS + s)) * NDP + c0;
    #pragma unroll
    for (int i = 0; i < 8; i++) pr[i] = acc[i];
}

__global__ void c_reduce(const float* __restrict__ part, float* __restrict__ c) {
    int b = blockIdx.x, d = threadIdx.x;
    float acc = 0.f;
    #pragma unroll
    for (int s = 0; s < JS; s++) acc += part[((size_t)(b * JS + s)) * NDP + d];
    if (d < ND) c[b * ND + d] = acc;
}

/* ---- GEMV partials: mode 0 q, 1 t, 2 m. grid (NB, JS) x 512 ---- */
__global__ void gemv_part(const float* __restrict__ x1, const float* __restrict__ x2,
                          const float* __restrict__ W, float* __restrict__ part, int mode) {
    int b = blockIdx.x, s = blockIdx.y, d = threadIdx.x;
    int j0 = s * 63, j1 = min(ND, j0 + 63);
    float acc = 0.f;
    if (d < ND) {
        if (mode == 0) {
            for (int j = j0; j < j1; j++)
                acc += x1[b * ND + j] * (W[(size_t)j * ND + d] + W[(size_t)(j + ND) * ND + d]);
        } else if (mode == 1) {
            for (int j = j0; j < j1; j++)
                acc += x1[b * ND + j] * W[(size_t)j * ND + d];
        } else {
            for (int j = j0; j < j1; j++) {
                acc += x1[b * ND + j] * W[(size_t)j * ND + d];
                acc += x2[b * ND + j] * (W[(size_t)(ND + j) * ND + d] + W[(size_t)(2 * ND + j) * ND + d]);
            }
        }
    }
    part[((size_t)(b * JS + s)) * NDP + d] = acc;
}

__global__ void gemv_reduce(const float* __restrict__ part, const float* __restrict__ bias,
                            const float* __restrict__ Wk, float* __restrict__ out) {
    int b = blockIdx.x, d = threadIdx.x;
    if (d >= ND) return;
    float acc = bias[d];
    #pragma unroll
    for (int s = 0; s < JS; s++) acc += part[((size_t)(b * JS + s)) * NDP + d];
    acc = fmaxf(acc, 0.f);
    if (Wk) acc *= Wk[d];
    out[b * ND + d] = acc;
}

/* ---- klog ---- */
__global__ void compute_klog(const bf16* __restrict__ g, const float* __restrict__ w2,
                             const float* __restrict__ Wk_b, float* __restrict__ klog) {
    int tok = blockIdx.x;
    int b = tok >> 10;
    int lane = threadIdx.x;
    const bf16* gr = g + (size_t)tok * NDP;
    const float* wr = w2 + b * ND;
    float acc = 0.f;
    for (int d = lane; d < ND; d += 64) acc += b2f(gr[d]) * wr[d];
    #pragma unroll
    for (int off = 32; off; off >>= 1) acc += __shfl_down(acc, off, 64);
    if (lane == 0) klog[tok] = acc + Wk_b[0];
}

/* ---- softmax over T ---- */
__global__ void softmax_k(const float* __restrict__ klog, float* __restrict__ k) {
    int b = blockIdx.x, tid = threadIdx.x;
    __shared__ float red[256];
    float m = -INFINITY;
    for (int t = tid; t < NT; t += 256) m = fmaxf(m, klog[b * NT + t]);
    red[tid] = m; __syncthreads();
    for (int s = 128; s; s >>= 1) { if (tid < s) red[tid] = fmaxf(red[tid], red[tid + s]); __syncthreads(); }
    m = red[0]; __syncthreads();
    float sum = 0.f;
    for (int t = tid; t < NT; t += 256) sum += expf(klog[b * NT + t] - m);
    red[tid] = sum; __syncthreads();
    for (int s = 128; s; s >>= 1) { if (tid < s) red[tid] += red[tid + s]; __syncthreads(); }
    float inv = 1.f / red[0];
    for (int t = tid; t < NT; t += 256) k[b * NT + t] = expf(klog[b * NT + t] - m) * inv;
}

/* ---- MFMA projections, all 3 in one dispatch (z = K/Q/V) ---- */
__global__ __launch_bounds__(256) void mfma_proj3(const bf16* __restrict__ g, const bf16* __restrict__ Wt_all,
                                                  const float* __restrict__ bK, const float* __restrict__ bQ,
                                                  const float* __restrict__ bV, bf16* __restrict__ kqv) {
    __shared__ short As[128 * LSTR], Bs[128 * LSTR];
    f32x4 acc[4][4] = {};
    int zz = blockIdx.z;
    const bf16* Wt = Wt_all + (size_t)zz * NDP * NDP;
    const float* bias = (zz == 0) ? bK : (zz == 1) ? bQ : bV;
    bf16* out = kqv + (size_t)zz * NTOK * NDP;
    int row0 = blockIdx.x * 128, col0 = blockIdx.y * 128;
    mfma_core(g + (size_t)row0 * NDP, NDP, Wt + (size_t)col0 * NDP, NDP, NDP / 32, As, Bs, acc);
    const int tid = threadIdx.x, lane = tid & 63, wave = tid >> 6;
    const int wx = wave & 1, wy = wave >> 1, m16 = lane & 15, quad = lane >> 4;
    #pragma unroll
    for (int j = 0; j < 4; j++) {
        int cg = col0 + wx * 64 + j * 16 + m16;
        float bv = (cg < ND) ? bias[cg] : 0.f;
        #pragma unroll
        for (int i = 0; i < 4; i++) {
            #pragma unroll
            for (int reg = 0; reg < 4; reg++) {
                int r = row0 + wy * 64 + i * 16 + quad * 4 + reg;
                float v = (cg < ND) ? (acc[i][j][reg] + bv) : 0.f;
                bf16 hv = __float2bfloat16(v);
                if (zz < 2) {
                    out[(size_t)r * NDP + cg] = hv;          /* [t][512] */
                } else {
                    int b = r >> 10, s = r & 1023;
                    out[((size_t)(b * NDP) + cg) * NT + s] = hv;  /* Vt[d][s] */
                }
            }
        }
    }
}

/* ---- MFMA S: bf16 out ---- */
__global__ __launch_bounds__(256) void mfma_S(const bf16* __restrict__ key, const bf16* __restrict__ query,
                                              bf16* __restrict__ S) {
    __shared__ short As[128 * LSTR], Bs[128 * LSTR];
    f32x4 acc[4][4] = {};
    int z = blockIdx.z;
    int row0 = blockIdx.x * 128, col0 = blockIdx.y * 128;
    const bf16* kb = key + (size_t)z * NT * NDP;
    const bf16* qb = query + (size_t)z * NT * NDP;
    mfma_core(kb + (size_t)row0 * NDP, NDP, qb + (size_t)col0 * NDP, NDP, NDP / 32, As, Bs, acc);
    bf16* Sb = S + ((size_t)z << 20);
    const int tid = threadIdx.x, lane = tid & 63, wave = tid >> 6;
    const int wx = wave & 1, wy = wave >> 1, m16 = lane & 15, quad = lane >> 4;
    #pragma unroll
    for (int i = 0; i < 4; i++)
        #pragma unroll
        for (int reg = 0; reg < 4; reg++) {
            size_t r = row0 + wy * 64 + i * 16 + quad * 4 + reg;
            #pragma unroll
            for (int j = 0; j < 4; j++) {
                int c = col0 + wx * 64 + j * 16 + m16;
                Sb[(r << 10) + c] = __float2bfloat16(acc[i][j][reg]);
            }
        }
}

/* ---- double softmax: one wave per row, shuffle butterflies, in-place P2 ---- */
__global__ __launch_bounds__(256) void attn_rows(bf16* __restrict__ S, float* __restrict__ att_out) {
    int gr = blockIdx.x * 4 + (threadIdx.x >> 6);     /* global row in [0, NB*NT) */
    int t = gr & 1023;
    int lane = threadIdx.x & 63;
    bf16* row = S + ((size_t)gr << 10) + lane * 16;
    short8 r0 = *(const short8*)row;
    short8 r1 = *(const short8*)(row + 8);
    float v[16];
    #pragma unroll
    for (int i = 0; i < 8; i++) { v[i] = b2f(((bf16*)&r0)[i]); v[8 + i] = b2f(((bf16*)&r1)[i]); }
    float m = -INFINITY;
    #pragma unroll
    for (int i = 0; i < 16; i++) m = fmaxf(m, v[i]);
    #pragma unroll
    for (int off = 32; off; off >>= 1) m = fmaxf(m, __shfl_xor(m, off, 64));
    float s1 = 0.f, s2 = 0.f, dg = 0.f;
    int tloc = t - lane * 16;
    #pragma unroll
    for (int i = 0; i < 16; i++) {
        float e1 = expf(v[i] - m);
        float e2 = expf((v[i] - m) * INV_SCALE);
        s1 += e1; s2 += e2;
        if (i == tloc) dg = e1;
        v[i] = e2;
    }
    #pragma unroll
    for (int off = 32; off; off >>= 1) {
        s1 += __shfl_xor(s1, off, 64);
        s2 += __shfl_xor(s2, off, 64);
        dg += __shfl_xor(dg, off, 64);
    }
    if (lane == 0) att_out[gr] = (1.f - dg / s1) * INV_SCALE;
    float inv2 = 1.f / s2;
    #pragma unroll
    for (int i = 0; i < 8; i++) {
        ((bf16*)&r0)[i] = __float2bfloat16(v[i] * inv2);
        ((bf16*)&r1)[i] = __float2bfloat16(v[8 + i] * inv2);
    }
    *(short8*)row = r0;
    *(short8*)(row + 8) = r1;
}

/* ---- MFMA PV: out = P2 @ V * mvec, fp32 out (stride 500) ---- */
__global__ __launch_bounds__(256) void mfma_PV(const bf16* __restrict__ S, const bf16* __restrict__ valueT,
                                               const float* __restrict__ mvec, float* __restrict__ outp) {
    __shared__ short As[128 * LSTR], Bs[128 * LSTR];
    f32x4 acc[4][4] = {};
    int z = blockIdx.z;
    int row0 = blockIdx.x * 128, col0 = blockIdx.y * 128;
    const bf16* P2 = S + ((size_t)z << 20);                  /* lda 1024 */
    const bf16* Vt = valueT + (size_t)z * NDP * NT;          /* ldb 1024 */
    mfma_core(P2 + (size_t)row0 * NT, NT, Vt + (size_t)col0 * NT, NT, NT / 32, As, Bs, acc);
    const int tid = threadIdx.x, lane = tid & 63, wave = tid >> 6;
    const int wx = wave & 1, wy = wave >> 1, m16 = lane & 15, quad = lane >> 4;
    #pragma unroll
    for (int j = 0; j < 4; j++) {
        int c = col0 + wx * 64 + j * 16 + m16;
        if (c >= ND) continue;
        float mm = mvec[z * ND + c];
        #pragma unroll
        for (int i = 0; i < 4; i++) {
            #pragma unroll
            for (int reg = 0; reg < 4; reg++) {
                int r = row0 + wy * 64 + i * 16 + quad * 4 + reg;
                outp[((size_t)(z * NT + r)) * ND + c] = acc[i][j][reg] * mm;
            }
        }
    }
}

extern "C" void kernel_launch(void* const* d_in, const int* in_sizes, int n_in,
                              void* d_out, int out_size, void* d_ws, size_t ws_size,
                              hipStream_t stream) {
    const int*   words     = (const int*)d_in[0];
    const int*   pos       = (const int*)d_in[2];
    const int*   ner       = (const int*)d_in[3];
    const int*   subj_pos  = (const int*)d_in[4];
    const int*   obj_pos   = (const int*)d_in[5];
    const int*   chunks    = (const int*)d_in[6];
    const int*   on_path   = (const int*)d_in[7];
    const float* dep_feat  = (const float*)d_in[8];
    const float* emb_w     = (const float*)d_in[9];
    const float* pos_w     = (const float*)d_in[10];
    const float* ner_w     = (const float*)d_in[11];
    const float* chunk_w   = (const float*)d_in[12];
    const float* position_w= (const float*)d_in[13];
    const float* Wq_w      = (const float*)d_in[14];
    const float* Wq_b      = (const float*)d_in[15];
    const float* Wc_w      = (const float*)d_in[16];
    const float* Wc_b      = (const float*)d_in[17];
    const float* Wk_w      = (const float*)d_in[18];
    const float* Wk_b      = (const float*)d_in[19];
    const float* Wm_w      = (const float*)d_in[20];
    const float* Wm_b      = (const float*)d_in[21];
    const float* K_w       = (const float*)d_in[22];
    const float* K_b       = (const float*)d_in[23];
    const float* Q_w       = (const float*)d_in[24];
    const float* Q_b       = (const float*)d_in[25];
    const float* V_w       = (const float*)d_in[26];
    const float* V_b       = (const float*)d_in[27];

    float* out_main = (float*)d_out;                       /* (B,T,500) fp32 */
    float* out_att  = out_main + (size_t)NTOK * ND;        /* (B,T) fp32 */

    /* ---- ws layout (~99 MB) ---- */
    char* wp = (char*)d_ws;
    float* subj = (float*)wp; wp += (size_t)NB * ND * 4;
    float* qb   = (float*)wp; wp += (size_t)NB * ND * 4;
    float* w2   = (float*)wp; wp += (size_t)NB * ND * 4;
    float* cb   = (float*)wp; wp += (size_t)NB * ND * 4;
    float* mv   = (float*)wp; wp += (size_t)NB * ND * 4;
    float* klog = (float*)wp; wp += (size_t)NB * NT * 4;
    float* kbuf = (float*)wp; wp += (size_t)NB * NT * 4;
    float* part = (float*)wp; wp += (size_t)NB * JS * NDP * 4;
    bf16* g     = (bf16*)wp;  wp += (size_t)NTOK * NDP * 2;
    bf16* Wt    = (bf16*)wp;  wp += (size_t)3 * NDP * NDP * 2;
    bf16* kqv   = (bf16*)wp;  wp += (size_t)3 * NTOK * NDP * 2;  /* key | query | Vt */
    bf16* S     = (bf16*)wp;                                     /* NB<<20 bf16 = 32 MB */

    bf16* key   = kqv;
    bf16* query = kqv + (size_t)NTOK * NDP;
    bf16* valT  = kqv + (size_t)2 * NTOK * NDP;

    transpose_w3<<<dim3(16, 16, 3), 256, 0, stream>>>(K_w, Q_w, V_w, Wt);

    /* phase A */
    build_g<<<NTOK, 128, 0, stream>>>(words, pos, ner, chunks, subj_pos, obj_pos,
                                      on_path, dep_feat, emb_w, pos_w, ner_w,
                                      chunk_w, position_w, g);
    pool_part<<<dim3(NB, JS), 64, 0, stream>>>(g, subj_pos, part);
    pool_reduce<<<NB, 512, 0, stream>>>(part, subj);
    gemv_part<<<dim3(NB, JS), 512, 0, stream>>>(subj, nullptr, Wq_w, part, 0);
    gemv_reduce<<<NB, 512, 0, stream>>>(part, Wq_b, nullptr, qb);
    gemv_part<<<dim3(NB, JS), 512, 0, stream>>>(qb, nullptr, Wc_w, part, 1);
    gemv_reduce<<<NB, 512, 0, stream>>>(part, Wc_b, Wk_w, w2);
    compute_klog<<<NTOK, 64, 0, stream>>>(g, w2, Wk_b, klog);
    softmax_k<<<NB, 256, 0, stream>>>(klog, kbuf);
    c_part<<<dim3(NB, JS), 64, 0, stream>>>(g, kbuf, part);
    c_reduce<<<NB, 512, 0, stream>>>(part, cb);
    gemv_part<<<dim3(NB, JS), 512, 0, stream>>>(cb, subj, Wm_w, part, 2);
    gemv_reduce<<<NB, 512, 0, stream>>>(part, Wm_b, nullptr, mv);

    /* phase B */
    mfma_proj3<<<dim3(NTOK / 128, NDP / 128, 3), 256, 0, stream>>>(g, Wt, K_b, Q_b, V_b, kqv);
    mfma_S<<<dim3(NT / 128, NT / 128, NB), 256, 0, stream>>>(key, query, S);
    attn_rows<<<NTOK / 4, 256, 0, stream>>>(S, out_att);
    mfma_PV<<<dim3(NT / 128, NDP / 128, NB), 256, 0, stream>>>(S, valT, mv, out_main);

    (void)in_sizes; (void)n_in; (void)out_size; (void)ws_size;
}

// Round 9
// 433.331 us; speedup vs baseline: 4.1626x; 1.0716x over previous
//
#include <hip/hip_runtime.h>
#include <hip/hip_bf16.h>

typedef __hip_bfloat16 bf16;
typedef __attribute__((ext_vector_type(8))) short short8;
typedef __attribute__((ext_vector_type(4))) short short4v;
typedef __attribute__((ext_vector_type(4))) float f32x4;

#define NB 16
#define NT 1024
#define ND 500
#define NDP 512               /* padded K/N for MFMA */
#define NTOK (NB * NT)
#define JS 8                  /* j split for GEMV kernels */
#define TSP 32                /* t split for pool/c kernels */
#define LSTR 40               /* LDS row stride in shorts */
#define INV_SCALE 0.04472135954999579f   /* 1/sqrt(500) */

__device__ __forceinline__ float b2f(bf16 x) { return __bfloat162float(x); }

/* ===================================================================== */
__device__ __forceinline__ void mfma_core(const bf16* __restrict__ Ab, int lda,
                                          const bf16* __restrict__ Bb, int ldb,
                                          int nsteps, short* As, short* Bs,
                                          f32x4 (&acc)[4][4]) {
    const int tid = threadIdx.x;
    const int lane = tid & 63;
    const int wave = tid >> 6;
    const int wx = wave & 1, wy = wave >> 1;
    const int m16 = lane & 15, quad = lane >> 4;
    const int row = tid >> 2, seg = tid & 3;
    const bf16* a0 = Ab + (size_t)row * lda + seg * 8;
    const bf16* a1 = a0 + (size_t)64 * lda;
    const bf16* b0 = Bb + (size_t)row * ldb + seg * 8;
    const bf16* b1 = b0 + (size_t)64 * ldb;
    short* asd0 = As + row * LSTR + seg * 8;
    short* asd1 = asd0 + 64 * LSTR;
    short* bsd0 = Bs + row * LSTR + seg * 8;
    short* bsd1 = bsd0 + 64 * LSTR;
    for (int ks = 0; ks < nsteps; ks++) {
        const int ko = ks * 32;
        *(short8*)asd0 = *(const short8*)(a0 + ko);
        *(short8*)asd1 = *(const short8*)(a1 + ko);
        *(short8*)bsd0 = *(const short8*)(b0 + ko);
        *(short8*)bsd1 = *(const short8*)(b1 + ko);
        __syncthreads();
        short8 af[4], bfv[4];
        #pragma unroll
        for (int i = 0; i < 4; i++)
            af[i] = *(const short8*)&As[(wy * 64 + i * 16 + m16) * LSTR + quad * 8];
        #pragma unroll
        for (int j = 0; j < 4; j++)
            bfv[j] = *(const short8*)&Bs[(wx * 64 + j * 16 + m16) * LSTR + quad * 8];
        #pragma unroll
        for (int i = 0; i < 4; i++)
            #pragma unroll
            for (int j = 0; j < 4; j++)
                acc[i][j] = __builtin_amdgcn_mfma_f32_16x16x32_bf16(af[i], bfv[j], acc[i][j], 0, 0, 0);
        __syncthreads();
    }
}

/* ---- W (500x500 fp32 [k][n]) -> Wt (512x512 bf16 [n][k]) ---- */
__global__ void transpose_w3(const float* __restrict__ WK, const float* __restrict__ WQ,
                             const float* __restrict__ WV, bf16* __restrict__ Wt_all) {
    const float* W = (blockIdx.z == 0) ? WK : (blockIdx.z == 1) ? WQ : WV;
    bf16* Wt = Wt_all + (size_t)blockIdx.z * NDP * NDP;
    __shared__ float t[32][33];
    int n0 = blockIdx.x * 32, k0 = blockIdx.y * 32;
    int a = threadIdx.x & 31, bq = threadIdx.x >> 5;
    #pragma unroll
    for (int it = 0; it < 4; it++) {
        int k = k0 + bq + it * 8, n = n0 + a;
        t[bq + it * 8][a] = (k < ND && n < ND) ? W[k * ND + n] : 0.f;
    }
    __syncthreads();
    #pragma unroll
    for (int it = 0; it < 4; it++) {
        int n = n0 + bq + it * 8;
        Wt[(size_t)n * NDP + k0 + a] = __float2bfloat16(t[a][bq + it * 8]);
    }
}

/* ---- value[t][512] bf16 -> Vt[b][c][s] bf16, 32x32 LDS tiles ---- */
__global__ void transpose_v(const bf16* __restrict__ val, bf16* __restrict__ Vt) {
    __shared__ bf16 tile[32][33];
    int b = blockIdx.z;
    int s0 = blockIdx.x * 32, c0 = blockIdx.y * 32;
    int r = threadIdx.x >> 3, q4 = (threadIdx.x & 7) * 4;
    /* read: row s0+r, cols c0+q4..+3 (coalesced 8B/thread) */
    const bf16* src = val + ((size_t)(b * NT + s0 + r)) * NDP + c0 + q4;
    *(short4v*)&tile[r][q4] = *(const short4v*)src;
    __syncthreads();
    /* write: row c0+r of Vt, s columns s0+q4..+3 (coalesced 8B/thread) */
    bf16* dst = Vt + ((size_t)(b * NDP + c0 + r)) * NT + s0 + q4;
    short4v o;
    #pragma unroll
    for (int i = 0; i < 4; i++) ((bf16*)&o)[i] = tile[q4 + i][r];
    *(short4v*)dst = o;
}

/* ---- build g (B,T,512) bf16, zero-padded cols >= 500 ---- */
__global__ void build_g(const int* __restrict__ words, const int* __restrict__ pos,
                        const int* __restrict__ ner, const int* __restrict__ chunks,
                        const int* __restrict__ subj_pos, const int* __restrict__ obj_pos,
                        const int* __restrict__ on_path, const float* __restrict__ dep_feat,
                        const float* __restrict__ emb_w, const float* __restrict__ pos_w,
                        const float* __restrict__ ner_w, const float* __restrict__ chunk_w,
                        const float* __restrict__ position_w, bf16* __restrict__ g) {
    int tok = blockIdx.x;
    int w = words[tok], p = pos[tok], n = ner[tok], ck = chunks[tok];
    int sp = subj_pos[tok], op = obj_pos[tok], onp = on_path[tok];
    bf16* gr = g + (size_t)tok * NDP;
    for (int d = threadIdx.x; d < NDP; d += blockDim.x) {
        float v;
        if      (d < 300) v = emb_w[(size_t)w * 300 + d];
        else if (d < 335) v = pos_w[p * 35 + (d - 300)];
        else if (d < 365) v = ner_w[n * 30 + (d - 335)];
        else if (d < 395) v = chunk_w[ck * 30 + (d - 365)];
        else if (d < 425) v = position_w[sp * 30 + (d - 395)];
        else if (d < 455) v = position_w[op * 30 + (d - 425)];
        else if (d == 455) v = (float)onp;
        else if (d < 500) v = dep_feat[(size_t)tok * 44 + (d - 456)];
        else              v = 0.f;
        gr[d] = __float2bfloat16(v);
    }
}

/* ---- subj max pool, split over t: grid (NB, TSP) x 64 ---- */
__global__ void pool_part(const bf16* __restrict__ g, const int* __restrict__ subj_pos,
                          float* __restrict__ part) {
    int b = blockIdx.x, s = blockIdx.y;
    int c0 = threadIdx.x * 8;
    const bf16* gb = g + (size_t)b * NT * NDP + c0;
    const int* sp = subj_pos + b * NT;
    float mx[8];
    #pragma unroll
    for (int i = 0; i < 8; i++) mx[i] = -INFINITY;
    int t0 = s * (NT / TSP), t1 = t0 + (NT / TSP);
    for (int t = t0; t < t1; t++) {
        int masked = (sp[t] != 0);
        short8 v8 = *(const short8*)(gb + (size_t)t * NDP);
        #pragma unroll
        for (int i = 0; i < 8; i++) {
            float v = masked ? -1e12f : b2f(((bf16*)&v8)[i]);
            mx[i] = fmaxf(mx[i], v);
        }
    }
    float* pr = part + ((size_t)(b * TSP + s)) * NDP + c0;
    #pragma unroll
    for (int i = 0; i < 8; i++) pr[i] = mx[i];
}

__global__ void pool_reduce(const float* __restrict__ part, float* __restrict__ subj) {
    int b = blockIdx.x, d = threadIdx.x;
    float mx = -INFINITY;
    #pragma unroll
    for (int s = 0; s < TSP; s++) mx = fmaxf(mx, part[((size_t)(b * TSP + s)) * NDP + d]);
    if (d < ND) subj[b * ND + d] = mx;
}

/* ---- c = sum_t k*g, split over t ---- */
__global__ void c_part(const bf16* __restrict__ g, const float* __restrict__ k,
                       float* __restrict__ part) {
    int b = blockIdx.x, s = blockIdx.y;
    int c0 = threadIdx.x * 8;
    const bf16* gb = g + (size_t)b * NT * NDP + c0;
    const float* kb = k + b * NT;
    float acc[8] = {};
    int t0 = s * (NT / TSP), t1 = t0 + (NT / TSP);
    for (int t = t0; t < t1; t++) {
        float kv = kb[t];
        short8 v8 = *(const short8*)(gb + (size_t)t * NDP);
        #pragma unroll
        for (int i = 0; i < 8; i++) acc[i] += kv * b2f(((bf16*)&v8)[i]);
    }
    float* pr = part + ((size_t)(b * TSP + s)) * NDP + c0;
    #pragma unroll
    for (int i = 0; i < 8; i++) pr[i] = acc[i];
}

__global__ void c_reduce(const float* __restrict__ part, float* __restrict__ c) {
    int b = blockIdx.x, d = threadIdx.x;
    float acc = 0.f;
    #pragma unroll
    for (int s = 0; s < TSP; s++) acc += part[((size_t)(b * TSP + s)) * NDP + d];
    if (d < ND) c[b * ND + d] = acc;
}

/* ---- GEMV partials: mode 0 q, 1 t, 2 m. grid (NB, JS) x 512 ---- */
__global__ void gemv_part(const float* __restrict__ x1, const float* __restrict__ x2,
                          const float* __restrict__ W, float* __restrict__ part, int mode) {
    int b = blockIdx.x, s = blockIdx.y, d = threadIdx.x;
    int j0 = s * 63, j1 = min(ND, j0 + 63);
    float acc = 0.f;
    if (d < ND) {
        if (mode == 0) {
            for (int j = j0; j < j1; j++)
                acc += x1[b * ND + j] * (W[(size_t)j * ND + d] + W[(size_t)(j + ND) * ND + d]);
        } else if (mode == 1) {
            for (int j = j0; j < j1; j++)
                acc += x1[b * ND + j] * W[(size_t)j * ND + d];
        } else {
            for (int j = j0; j < j1; j++) {
                acc += x1[b * ND + j] * W[(size_t)j * ND + d];
                acc += x2[b * ND + j] * (W[(size_t)(ND + j) * ND + d] + W[(size_t)(2 * ND + j) * ND + d]);
            }
        }
    }
    part[((size_t)(b * JS + s)) * NDP + d] = acc;
}

__global__ void gemv_reduce(const float* __restrict__ part, const float* __restrict__ bias,
                            const float* __restrict__ Wk, float* __restrict__ out) {
    int b = blockIdx.x, d = threadIdx.x;
    if (d >= ND) return;
    float acc = bias[d];
    #pragma unroll
    for (int s = 0; s < JS; s++) acc += part[((size_t)(b * JS + s)) * NDP + d];
    acc = fmaxf(acc, 0.f);
    if (Wk) acc *= Wk[d];
    out[b * ND + d] = acc;
}

/* ---- klog: 4 waves/block, one token per wave, short8 vector loads ---- */
__global__ void compute_klog(const bf16* __restrict__ g, const float* __restrict__ w2,
                             const float* __restrict__ Wk_b, float* __restrict__ klog) {
    int tok = blockIdx.x * 4 + (threadIdx.x >> 6);
    int lane = threadIdx.x & 63;
    int b = tok >> 10;
    const bf16* gr = g + (size_t)tok * NDP + lane * 8;
    const float* wr = w2 + b * ND + lane * 8;   /* overreads past 500 hit finite ws floats x g=0 */
    short8 v8 = *(const short8*)gr;
    float acc = 0.f;
    #pragma unroll
    for (int i = 0; i < 8; i++) acc += b2f(((bf16*)&v8)[i]) * wr[i];
    #pragma unroll
    for (int off = 32; off; off >>= 1) acc += __shfl_down(acc, off, 64);
    if (lane == 0) klog[tok] = acc + Wk_b[0];
}

/* ---- softmax over T ---- */
__global__ void softmax_k(const float* __restrict__ klog, float* __restrict__ k) {
    int b = blockIdx.x, tid = threadIdx.x;
    __shared__ float red[256];
    float m = -INFINITY;
    for (int t = tid; t < NT; t += 256) m = fmaxf(m, klog[b * NT + t]);
    red[tid] = m; __syncthreads();
    for (int s = 128; s; s >>= 1) { if (tid < s) red[tid] = fmaxf(red[tid], red[tid + s]); __syncthreads(); }
    m = red[0]; __syncthreads();
    float sum = 0.f;
    for (int t = tid; t < NT; t += 256) sum += expf(klog[b * NT + t] - m);
    red[tid] = sum; __syncthreads();
    for (int s = 128; s; s >>= 1) { if (tid < s) red[tid] += red[tid + s]; __syncthreads(); }
    float inv = 1.f / red[0];
    for (int t = tid; t < NT; t += 256) k[b * NT + t] = expf(klog[b * NT + t] - m) * inv;
}

/* ---- MFMA projections, all 3 in one dispatch, all coalesced [t][512] ---- */
__global__ __launch_bounds__(256) void mfma_proj3(const bf16* __restrict__ g, const bf16* __restrict__ Wt_all,
                                                  const float* __restrict__ bK, const float* __restrict__ bQ,
                                                  const float* __restrict__ bV, bf16* __restrict__ kqv) {
    __shared__ short As[128 * LSTR], Bs[128 * LSTR];
    f32x4 acc[4][4] = {};
    int zz = blockIdx.z;
    const bf16* Wt = Wt_all + (size_t)zz * NDP * NDP;
    const float* bias = (zz == 0) ? bK : (zz == 1) ? bQ : bV;
    bf16* out = kqv + (size_t)zz * NTOK * NDP;
    int row0 = blockIdx.x * 128, col0 = blockIdx.y * 128;
    mfma_core(g + (size_t)row0 * NDP, NDP, Wt + (size_t)col0 * NDP, NDP, NDP / 32, As, Bs, acc);
    const int tid = threadIdx.x, lane = tid & 63, wave = tid >> 6;
    const int wx = wave & 1, wy = wave >> 1, m16 = lane & 15, quad = lane >> 4;
    #pragma unroll
    for (int j = 0; j < 4; j++) {
        int cg = col0 + wx * 64 + j * 16 + m16;
        float bv = (cg < ND) ? bias[cg] : 0.f;
        #pragma unroll
        for (int i = 0; i < 4; i++) {
            #pragma unroll
            for (int reg = 0; reg < 4; reg++) {
                int r = row0 + wy * 64 + i * 16 + quad * 4 + reg;
                float v = (cg < ND) ? (acc[i][j][reg] + bv) : 0.f;
                out[(size_t)r * NDP + cg] = __float2bfloat16(v);
            }
        }
    }
}

/* ---- MFMA S: bf16 out ---- */
__global__ __launch_bounds__(256) void mfma_S(const bf16* __restrict__ key, const bf16* __restrict__ query,
                                              bf16* __restrict__ S) {
    __shared__ short As[128 * LSTR], Bs[128 * LSTR];
    f32x4 acc[4][4] = {};
    int z = blockIdx.z;
    int row0 = blockIdx.x * 128, col0 = blockIdx.y * 128;
    const bf16* kb = key + (size_t)z * NT * NDP;
    const bf16* qb = query + (size_t)z * NT * NDP;
    mfma_core(kb + (size_t)row0 * NDP, NDP, qb + (size_t)col0 * NDP, NDP, NDP / 32, As, Bs, acc);
    bf16* Sb = S + ((size_t)z << 20);
    const int tid = threadIdx.x, lane = tid & 63, wave = tid >> 6;
    const int wx = wave & 1, wy = wave >> 1, m16 = lane & 15, quad = lane >> 4;
    #pragma unroll
    for (int i = 0; i < 4; i++)
        #pragma unroll
        for (int reg = 0; reg < 4; reg++) {
            size_t r = row0 + wy * 64 + i * 16 + quad * 4 + reg;
            #pragma unroll
            for (int j = 0; j < 4; j++) {
                int c = col0 + wx * 64 + j * 16 + m16;
                Sb[(r << 10) + c] = __float2bfloat16(acc[i][j][reg]);
            }
        }
}

/* ---- double softmax: one wave per row, in-place P2 ---- */
__global__ __launch_bounds__(256) void attn_rows(bf16* __restrict__ S, float* __restrict__ att_out) {
    int gr = blockIdx.x * 4 + (threadIdx.x >> 6);
    int t = gr & 1023;
    int lane = threadIdx.x & 63;
    bf16* row = S + ((size_t)gr << 10) + lane * 16;
    short8 r0 = *(const short8*)row;
    short8 r1 = *(const short8*)(row + 8);
    float v[16];
    #pragma unroll
    for (int i = 0; i < 8; i++) { v[i] = b2f(((bf16*)&r0)[i]); v[8 + i] = b2f(((bf16*)&r1)[i]); }
    float m = -INFINITY;
    #pragma unroll
    for (int i = 0; i < 16; i++) m = fmaxf(m, v[i]);
    #pragma unroll
    for (int off = 32; off; off >>= 1) m = fmaxf(m, __shfl_xor(m, off, 64));
    float s1 = 0.f, s2 = 0.f, dg = 0.f;
    int tloc = t - lane * 16;
    #pragma unroll
    for (int i = 0; i < 16; i++) {
        float e1 = expf(v[i] - m);
        float e2 = expf((v[i] - m) * INV_SCALE);
        s1 += e1; s2 += e2;
        if (i == tloc) dg = e1;
        v[i] = e2;
    }
    #pragma unroll
    for (int off = 32; off; off >>= 1) {
        s1 += __shfl_xor(s1, off, 64);
        s2 += __shfl_xor(s2, off, 64);
        dg += __shfl_xor(dg, off, 64);
    }
    if (lane == 0) att_out[gr] = (1.f - dg / s1) * INV_SCALE;
    float inv2 = 1.f / s2;
    #pragma unroll
    for (int i = 0; i < 8; i++) {
        ((bf16*)&r0)[i] = __float2bfloat16(v[i] * inv2);
        ((bf16*)&r1)[i] = __float2bfloat16(v[8 + i] * inv2);
    }
    *(short8*)row = r0;
    *(short8*)(row + 8) = r1;
}

/* ---- MFMA PV: out = P2 @ V * mvec, fp32 out (stride 500) ---- */
__global__ __launch_bounds__(256) void mfma_PV(const bf16* __restrict__ S, const bf16* __restrict__ valueT,
                                               const float* __restrict__ mvec, float* __restrict__ outp) {
    __shared__ short As[128 * LSTR], Bs[128 * LSTR];
    f32x4 acc[4][4] = {};
    int z = blockIdx.z;
    int row0 = blockIdx.x * 128, col0 = blockIdx.y * 128;
    const bf16* P2 = S + ((size_t)z << 20);
    const bf16* Vt = valueT + (size_t)z * NDP * NT;
    mfma_core(P2 + (size_t)row0 * NT, NT, Vt + (size_t)col0 * NT, NT, NT / 32, As, Bs, acc);
    const int tid = threadIdx.x, lane = tid & 63, wave = tid >> 6;
    const int wx = wave & 1, wy = wave >> 1, m16 = lane & 15, quad = lane >> 4;
    #pragma unroll
    for (int j = 0; j < 4; j++) {
        int c = col0 + wx * 64 + j * 16 + m16;
        if (c >= ND) continue;
        float mm = mvec[z * ND + c];
        #pragma unroll
        for (int i = 0; i < 4; i++) {
            #pragma unroll
            for (int reg = 0; reg < 4; reg++) {
                int r = row0 + wy * 64 + i * 16 + quad * 4 + reg;
                outp[((size_t)(z * NT + r)) * ND + c] = acc[i][j][reg] * mm;
            }
        }
    }
}

extern "C" void kernel_launch(void* const* d_in, const int* in_sizes, int n_in,
                              void* d_out, int out_size, void* d_ws, size_t ws_size,
                              hipStream_t stream) {
    const int*   words     = (const int*)d_in[0];
    const int*   pos       = (const int*)d_in[2];
    const int*   ner       = (const int*)d_in[3];
    const int*   subj_pos  = (const int*)d_in[4];
    const int*   obj_pos   = (const int*)d_in[5];
    const int*   chunks    = (const int*)d_in[6];
    const int*   on_path   = (const int*)d_in[7];
    const float* dep_feat  = (const float*)d_in[8];
    const float* emb_w     = (const float*)d_in[9];
    const float* pos_w     = (const float*)d_in[10];
    const float* ner_w     = (const float*)d_in[11];
    const float* chunk_w   = (const float*)d_in[12];
    const float* position_w= (const float*)d_in[13];
    const float* Wq_w      = (const float*)d_in[14];
    const float* Wq_b      = (const float*)d_in[15];
    const float* Wc_w      = (const float*)d_in[16];
    const float* Wc_b      = (const float*)d_in[17];
    const float* Wk_w      = (const float*)d_in[18];
    const float* Wk_b      = (const float*)d_in[19];
    const float* Wm_w      = (const float*)d_in[20];
    const float* Wm_b      = (const float*)d_in[21];
    const float* K_w       = (const float*)d_in[22];
    const float* K_b       = (const float*)d_in[23];
    const float* Q_w       = (const float*)d_in[24];
    const float* Q_b       = (const float*)d_in[25];
    const float* V_w       = (const float*)d_in[26];
    const float* V_b       = (const float*)d_in[27];

    float* out_main = (float*)d_out;
    float* out_att  = out_main + (size_t)NTOK * ND;

    /* ---- ws layout (~116 MB) ---- */
    char* wp = (char*)d_ws;
    float* subj = (float*)wp; wp += (size_t)NB * ND * 4;
    float* qb   = (float*)wp; wp += (size_t)NB * ND * 4;
    float* w2   = (float*)wp; wp += (size_t)NB * ND * 4;
    float* cb   = (float*)wp; wp += (size_t)NB * ND * 4;
    float* mv   = (float*)wp; wp += (size_t)NB * ND * 4;
    float* klog = (float*)wp; wp += (size_t)NB * NT * 4;
    float* kbuf = (float*)wp; wp += (size_t)NB * NT * 4;
    float* part = (float*)wp; wp += (size_t)NB * TSP * NDP * 4;
    bf16* g     = (bf16*)wp;  wp += (size_t)NTOK * NDP * 2;
    bf16* Wt    = (bf16*)wp;  wp += (size_t)3 * NDP * NDP * 2;
    bf16* kqv   = (bf16*)wp;  wp += (size_t)3 * NTOK * NDP * 2;  /* key | query | value */
    bf16* valT  = (bf16*)wp;  wp += (size_t)NTOK * NDP * 2;      /* Vt[b][c][s] */
    bf16* S     = (bf16*)wp;                                     /* NB<<20 bf16 = 32 MB */

    bf16* key   = kqv;
    bf16* query = kqv + (size_t)NTOK * NDP;
    bf16* value = kqv + (size_t)2 * NTOK * NDP;

    transpose_w3<<<dim3(16, 16, 3), 256, 0, stream>>>(K_w, Q_w, V_w, Wt);

    /* phase A */
    build_g<<<NTOK, 128, 0, stream>>>(words, pos, ner, chunks, subj_pos, obj_pos,
                                      on_path, dep_feat, emb_w, pos_w, ner_w,
                                      chunk_w, position_w, g);
    pool_part<<<dim3(NB, TSP), 64, 0, stream>>>(g, subj_pos, part);
    pool_reduce<<<NB, 512, 0, stream>>>(part, subj);
    gemv_part<<<dim3(NB, JS), 512, 0, stream>>>(subj, nullptr, Wq_w, part, 0);
    gemv_reduce<<<NB, 512, 0, stream>>>(part, Wq_b, nullptr, qb);
    gemv_part<<<dim3(NB, JS), 512, 0, stream>>>(qb, nullptr, Wc_w, part, 1);
    gemv_reduce<<<NB, 512, 0, stream>>>(part, Wc_b, Wk_w, w2);
    compute_klog<<<NTOK / 4, 256, 0, stream>>>(g, w2, Wk_b, klog);
    softmax_k<<<NB, 256, 0, stream>>>(klog, kbuf);
    c_part<<<dim3(NB, TSP), 64, 0, stream>>>(g, kbuf, part);
    c_reduce<<<NB, 512, 0, stream>>>(part, cb);
    gemv_part<<<dim3(NB, JS), 512, 0, stream>>>(cb, subj, Wm_w, part, 2);
    gemv_reduce<<<NB, 512, 0, stream>>>(part, Wm_b, nullptr, mv);

    /* phase B */
    mfma_proj3<<<dim3(NTOK / 128, NDP / 128, 3), 256, 0, stream>>>(g, Wt, K_b, Q_b, V_b, kqv);
    transpose_v<<<dim3(NT / 32, NDP / 32, NB), 256, 0, stream>>>(value, valT);
    mfma_S<<<dim3(NT / 128, NT / 128, NB), 256, 0, stream>>>(key, query, S);
    attn_rows<<<NTOK / 4, 256, 0, stream>>>(S, out_att);
    mfma_PV<<<dim3(NT / 128, NDP / 128, NB), 256, 0, stream>>>(S, valT, mv, out_main);

    (void)in_sizes; (void)n_in; (void)out_size; (void)ws_size;
}

// Round 10
// 429.866 us; speedup vs baseline: 4.1961x; 1.0081x over previous
//
#include <hip/hip_runtime.h>
#include <hip/hip_bf16.h>

typedef __hip_bfloat16 bf16;
typedef __attribute__((ext_vector_type(8))) short short8;
typedef __attribute__((ext_vector_type(4))) short short4v;
typedef __attribute__((ext_vector_type(4))) float f32x4;

#define NB 16
#define NT 1024
#define ND 500
#define NDP 512               /* padded K/N for MFMA */
#define NTOK (NB * NT)
#define JS 8                  /* j split for GEMV kernels */
#define TSP 32                /* t split for pool/c kernels */
#define LSTR 32               /* LDS row stride in shorts (global_load_lds needs lane*16B contiguity) */
#define INV_SCALE 0.04472135954999579f   /* 1/sqrt(500) */

__device__ __forceinline__ float b2f(bf16 x) { return __bfloat162float(x); }

/* async 16B global -> LDS (direct-to-shared DMA; lane i lands at ldsbase + i*16B) */
__device__ __forceinline__ void gload_lds16(const bf16* g, short* l) {
    __builtin_amdgcn_global_load_lds((const __attribute__((address_space(1))) void*)g,
                                     (__attribute__((address_space(3))) void*)l, 16, 0, 0);
}

/* =====================================================================
 * MFMA core: 128x128 tile, 4 waves (2x2), each wave 4x4 of 16x16x32.
 * Staging via global_load_lds width=16: per wave, lane i loads
 * row (wave*16 + i/4), seg (i%4) -> LDS base + i*16B (LSTR=32 layout).
 * ===================================================================== */
__device__ __forceinline__ void mfma_core(const bf16* __restrict__ Ab, int lda,
                                          const bf16* __restrict__ Bb, int ldb,
                                          int nsteps, short* As, short* Bs,
                                          f32x4 (&acc)[4][4]) {
    const int tid = threadIdx.x;
    const int lane = tid & 63;
    const int wave = tid >> 6;
    const int wy = wave >> 1, wx = wave & 1;
    const int m16 = lane & 15, quad = lane >> 4;
    const int srow = wave * 16 + (lane >> 2);
    const int sseg = lane & 3;
    const bf16* a0 = Ab + (size_t)srow * lda + sseg * 8;
    const bf16* a1 = a0 + (size_t)64 * lda;
    const bf16* b0 = Bb + (size_t)srow * ldb + sseg * 8;
    const bf16* b1 = b0 + (size_t)64 * ldb;
    short* aL0 = As + wave * 512;          /* wave-uniform LDS dests */
    short* aL1 = As + 2048 + wave * 512;
    short* bL0 = Bs + wave * 512;
    short* bL1 = Bs + 2048 + wave * 512;
    for (int ks = 0; ks < nsteps; ks++) {
        const int ko = ks * 32;
        gload_lds16(a0 + ko, aL0);
        gload_lds16(a1 + ko, aL1);
        gload_lds16(b0 + ko, bL0);
        gload_lds16(b1 + ko, bL1);
        __syncthreads();
        short8 af[4], bfv[4];
        #pragma unroll
        for (int i = 0; i < 4; i++)
            af[i] = *(const short8*)&As[(wy * 64 + i * 16 + m16) * LSTR + quad * 8];
        #pragma unroll
        for (int j = 0; j < 4; j++)
            bfv[j] = *(const short8*)&Bs[(wx * 64 + j * 16 + m16) * LSTR + quad * 8];
        #pragma unroll
        for (int i = 0; i < 4; i++)
            #pragma unroll
            for (int j = 0; j < 4; j++)
                acc[i][j] = __builtin_amdgcn_mfma_f32_16x16x32_bf16(af[i], bfv[j], acc[i][j], 0, 0, 0);
        __syncthreads();
    }
}

/* ---- W (500x500 fp32 [k][n]) -> Wt (512x512 bf16 [n][k]) ---- */
__global__ void transpose_w3(const float* __restrict__ WK, const float* __restrict__ WQ,
                             const float* __restrict__ WV, bf16* __restrict__ Wt_all) {
    const float* W = (blockIdx.z == 0) ? WK : (blockIdx.z == 1) ? WQ : WV;
    bf16* Wt = Wt_all + (size_t)blockIdx.z * NDP * NDP;
    __shared__ float t[32][33];
    int n0 = blockIdx.x * 32, k0 = blockIdx.y * 32;
    int a = threadIdx.x & 31, bq = threadIdx.x >> 5;
    #pragma unroll
    for (int it = 0; it < 4; it++) {
        int k = k0 + bq + it * 8, n = n0 + a;
        t[bq + it * 8][a] = (k < ND && n < ND) ? W[k * ND + n] : 0.f;
    }
    __syncthreads();
    #pragma unroll
    for (int it = 0; it < 4; it++) {
        int n = n0 + bq + it * 8;
        Wt[(size_t)n * NDP + k0 + a] = __float2bfloat16(t[a][bq + it * 8]);
    }
}

/* ---- value[t][512] bf16 -> Vt[b][c][s] bf16 ---- */
__global__ void transpose_v(const bf16* __restrict__ val, bf16* __restrict__ Vt) {
    __shared__ bf16 tile[32][33];
    int b = blockIdx.z;
    int s0 = blockIdx.x * 32, c0 = blockIdx.y * 32;
    int r = threadIdx.x >> 3, q4 = (threadIdx.x & 7) * 4;
    const bf16* src = val + ((size_t)(b * NT + s0 + r)) * NDP + c0 + q4;
    *(short4v*)&tile[r][q4] = *(const short4v*)src;
    __syncthreads();
    bf16* dst = Vt + ((size_t)(b * NDP + c0 + r)) * NT + s0 + q4;
    short4v o;
    #pragma unroll
    for (int i = 0; i < 4; i++) ((bf16*)&o)[i] = tile[q4 + i][r];
    *(short4v*)dst = o;
}

/* ---- build g (B,T,512) bf16 ---- */
__global__ void build_g(const int* __restrict__ words, const int* __restrict__ pos,
                        const int* __restrict__ ner, const int* __restrict__ chunks,
                        const int* __restrict__ subj_pos, const int* __restrict__ obj_pos,
                        const int* __restrict__ on_path, const float* __restrict__ dep_feat,
                        const float* __restrict__ emb_w, const float* __restrict__ pos_w,
                        const float* __restrict__ ner_w, const float* __restrict__ chunk_w,
                        const float* __restrict__ position_w, bf16* __restrict__ g) {
    int tok = blockIdx.x;
    int w = words[tok], p = pos[tok], n = ner[tok], ck = chunks[tok];
    int sp = subj_pos[tok], op = obj_pos[tok], onp = on_path[tok];
    bf16* gr = g + (size_t)tok * NDP;
    for (int d = threadIdx.x; d < NDP; d += blockDim.x) {
        float v;
        if      (d < 300) v = emb_w[(size_t)w * 300 + d];
        else if (d < 335) v = pos_w[p * 35 + (d - 300)];
        else if (d < 365) v = ner_w[n * 30 + (d - 335)];
        else if (d < 395) v = chunk_w[ck * 30 + (d - 365)];
        else if (d < 425) v = position_w[sp * 30 + (d - 395)];
        else if (d < 455) v = position_w[op * 30 + (d - 425)];
        else if (d == 455) v = (float)onp;
        else if (d < 500) v = dep_feat[(size_t)tok * 44 + (d - 456)];
        else              v = 0.f;
        gr[d] = __float2bfloat16(v);
    }
}

/* ---- subj max pool ---- */
__global__ void pool_part(const bf16* __restrict__ g, const int* __restrict__ subj_pos,
                          float* __restrict__ part) {
    int b = blockIdx.x, s = blockIdx.y;
    int c0 = threadIdx.x * 8;
    const bf16* gb = g + (size_t)b * NT * NDP + c0;
    const int* sp = subj_pos + b * NT;
    float mx[8];
    #pragma unroll
    for (int i = 0; i < 8; i++) mx[i] = -INFINITY;
    int t0 = s * (NT / TSP), t1 = t0 + (NT / TSP);
    for (int t = t0; t < t1; t++) {
        int masked = (sp[t] != 0);
        short8 v8 = *(const short8*)(gb + (size_t)t * NDP);
        #pragma unroll
        for (int i = 0; i < 8; i++) {
            float v = masked ? -1e12f : b2f(((bf16*)&v8)[i]);
            mx[i] = fmaxf(mx[i], v);
        }
    }
    float* pr = part + ((size_t)(b * TSP + s)) * NDP + c0;
    #pragma unroll
    for (int i = 0; i < 8; i++) pr[i] = mx[i];
}

__global__ void pool_reduce(const float* __restrict__ part, float* __restrict__ subj) {
    int b = blockIdx.x, d = threadIdx.x;
    float mx = -INFINITY;
    #pragma unroll
    for (int s = 0; s < TSP; s++) mx = fmaxf(mx, part[((size_t)(b * TSP + s)) * NDP + d]);
    if (d < ND) subj[b * ND + d] = mx;
}

/* ---- c = sum_t k*g ---- */
__global__ void c_part(const bf16* __restrict__ g, const float* __restrict__ k,
                       float* __restrict__ part) {
    int b = blockIdx.x, s = blockIdx.y;
    int c0 = threadIdx.x * 8;
    const bf16* gb = g + (size_t)b * NT * NDP + c0;
    const float* kb = k + b * NT;
    float acc[8] = {};
    int t0 = s * (NT / TSP), t1 = t0 + (NT / TSP);
    for (int t = t0; t < t1; t++) {
        float kv = kb[t];
        short8 v8 = *(const short8*)(gb + (size_t)t * NDP);
        #pragma unroll
        for (int i = 0; i < 8; i++) acc[i] += kv * b2f(((bf16*)&v8)[i]);
    }
    float* pr = part + ((size_t)(b * TSP + s)) * NDP + c0;
    #pragma unroll
    for (int i = 0; i < 8; i++) pr[i] = acc[i];
}

__global__ void c_reduce(const float* __restrict__ part, float* __restrict__ c) {
    int b = blockIdx.x, d = threadIdx.x;
    float acc = 0.f;
    #pragma unroll
    for (int s = 0; s < TSP; s++) acc += part[((size_t)(b * TSP + s)) * NDP + d];
    if (d < ND) c[b * ND + d] = acc;
}

/* ---- GEMV partials: mode 0 q, 1 t, 2 m ---- */
__global__ void gemv_part(const float* __restrict__ x1, const float* __restrict__ x2,
                          const float* __restrict__ W, float* __restrict__ part, int mode) {
    int b = blockIdx.x, s = blockIdx.y, d = threadIdx.x;
    int j0 = s * 63, j1 = min(ND, j0 + 63);
    float acc = 0.f;
    if (d < ND) {
        if (mode == 0) {
            for (int j = j0; j < j1; j++)
                acc += x1[b * ND + j] * (W[(size_t)j * ND + d] + W[(size_t)(j + ND) * ND + d]);
        } else if (mode == 1) {
            for (int j = j0; j < j1; j++)
                acc += x1[b * ND + j] * W[(size_t)j * ND + d];
        } else {
            for (int j = j0; j < j1; j++) {
                acc += x1[b * ND + j] * W[(size_t)j * ND + d];
                acc += x2[b * ND + j] * (W[(size_t)(ND + j) * ND + d] + W[(size_t)(2 * ND + j) * ND + d]);
            }
        }
    }
    part[((size_t)(b * JS + s)) * NDP + d] = acc;
}

__global__ void gemv_reduce(const float* __restrict__ part, const float* __restrict__ bias,
                            const float* __restrict__ Wk, float* __restrict__ out) {
    int b = blockIdx.x, d = threadIdx.x;
    if (d >= ND) return;
    float acc = bias[d];
    #pragma unroll
    for (int s = 0; s < JS; s++) acc += part[((size_t)(b * JS + s)) * NDP + d];
    acc = fmaxf(acc, 0.f);
    if (Wk) acc *= Wk[d];
    out[b * ND + d] = acc;
}

/* ---- klog ---- */
__global__ void compute_klog(const bf16* __restrict__ g, const float* __restrict__ w2,
                             const float* __restrict__ Wk_b, float* __restrict__ klog) {
    int tok = blockIdx.x * 4 + (threadIdx.x >> 6);
    int lane = threadIdx.x & 63;
    int b = tok >> 10;
    const bf16* gr = g + (size_t)tok * NDP + lane * 8;
    const float* wr = w2 + b * ND + lane * 8;
    short8 v8 = *(const short8*)gr;
    float acc = 0.f;
    #pragma unroll
    for (int i = 0; i < 8; i++) acc += b2f(((bf16*)&v8)[i]) * wr[i];
    #pragma unroll
    for (int off = 32; off; off >>= 1) acc += __shfl_down(acc, off, 64);
    if (lane == 0) klog[tok] = acc + Wk_b[0];
}

/* ---- softmax over T ---- */
__global__ void softmax_k(const float* __restrict__ klog, float* __restrict__ k) {
    int b = blockIdx.x, tid = threadIdx.x;
    __shared__ float red[256];
    float m = -INFINITY;
    for (int t = tid; t < NT; t += 256) m = fmaxf(m, klog[b * NT + t]);
    red[tid] = m; __syncthreads();
    for (int s = 128; s; s >>= 1) { if (tid < s) red[tid] = fmaxf(red[tid], red[tid + s]); __syncthreads(); }
    m = red[0]; __syncthreads();
    float sum = 0.f;
    for (int t = tid; t < NT; t += 256) sum += expf(klog[b * NT + t] - m);
    red[tid] = sum; __syncthreads();
    for (int s = 128; s; s >>= 1) { if (tid < s) red[tid] += red[tid + s]; __syncthreads(); }
    float inv = 1.f / red[0];
    for (int t = tid; t < NT; t += 256) k[b * NT + t] = expf(klog[b * NT + t] - m) * inv;
}

/* ---- MFMA projections (K/Q/V via z), LDS-restaged coalesced epilogue ---- */
__global__ __launch_bounds__(256) void mfma_proj3(const bf16* __restrict__ g, const bf16* __restrict__ Wt_all,
                                                  const float* __restrict__ bK, const float* __restrict__ bQ,
                                                  const float* __restrict__ bV, bf16* __restrict__ kqv) {
    __shared__ short LB[8192];
    short* As = LB;
    short* Bs = LB + 4096;
    f32x4 acc[4][4] = {};
    int zz = blockIdx.z;
    const bf16* Wt = Wt_all + (size_t)zz * NDP * NDP;
    const float* bias = (zz == 0) ? bK : (zz == 1) ? bQ : bV;
    bf16* out = kqv + (size_t)zz * NTOK * NDP;
    int row0 = blockIdx.x * 128, col0 = blockIdx.y * 128;
    mfma_core(g + (size_t)row0 * NDP, NDP, Wt + (size_t)col0 * NDP, NDP, NDP / 32, As, Bs, acc);
    const int tid = threadIdx.x, lane = tid & 63, wave = tid >> 6;
    const int wx = wave & 1, wy = wave >> 1, m16 = lane & 15, quad = lane >> 4;
    bf16* Ct = (bf16*)LB;                 /* 64 x 128 bf16 half-tile */
    int rl = tid >> 4, cs = (tid & 15) * 8;
    #pragma unroll
    for (int h = 0; h < 2; h++) {
        if (wy == h) {
            #pragma unroll
            for (int j = 0; j < 4; j++) {
                int cl = wx * 64 + j * 16 + m16;
                int cg = col0 + cl;
                float bv = (cg < ND) ? bias[cg] : 0.f;
                bool ok = (cg < ND);
                #pragma unroll
                for (int i = 0; i < 4; i++)
                    #pragma unroll
                    for (int reg = 0; reg < 4; reg++)
                        Ct[(i * 16 + quad * 4 + reg) * 128 + cl] =
                            __float2bfloat16(ok ? (acc[i][j][reg] + bv) : 0.f);
            }
        }
        __syncthreads();
        #pragma unroll
        for (int p = 0; p < 4; p++) {
            int row_l = p * 16 + rl;
            *(short8*)(out + (size_t)(row0 + h * 64 + row_l) * NDP + col0 + cs) =
                *(const short8*)&Ct[row_l * 128 + cs];
        }
        __syncthreads();
    }
}

/* ---- MFMA S: bf16 out, coalesced epilogue ---- */
__global__ __launch_bounds__(256) void mfma_S(const bf16* __restrict__ key, const bf16* __restrict__ query,
                                              bf16* __restrict__ S) {
    __shared__ short LB[8192];
    short* As = LB;
    short* Bs = LB + 4096;
    f32x4 acc[4][4] = {};
    int z = blockIdx.z;
    int row0 = blockIdx.x * 128, col0 = blockIdx.y * 128;
    const bf16* kb = key + (size_t)z * NT * NDP;
    const bf16* qb = query + (size_t)z * NT * NDP;
    mfma_core(kb + (size_t)row0 * NDP, NDP, qb + (size_t)col0 * NDP, NDP, NDP / 32, As, Bs, acc);
    bf16* Sb = S + ((size_t)z << 20);
    const int tid = threadIdx.x, lane = tid & 63, wave = tid >> 6;
    const int wx = wave & 1, wy = wave >> 1, m16 = lane & 15, quad = lane >> 4;
    bf16* Ct = (bf16*)LB;
    int rl = tid >> 4, cs = (tid & 15) * 8;
    #pragma unroll
    for (int h = 0; h < 2; h++) {
        if (wy == h) {
            #pragma unroll
            for (int j = 0; j < 4; j++) {
                int cl = wx * 64 + j * 16 + m16;
                #pragma unroll
                for (int i = 0; i < 4; i++)
                    #pragma unroll
                    for (int reg = 0; reg < 4; reg++)
                        Ct[(i * 16 + quad * 4 + reg) * 128 + cl] = __float2bfloat16(acc[i][j][reg]);
            }
        }
        __syncthreads();
        #pragma unroll
        for (int p = 0; p < 4; p++) {
            int row_l = p * 16 + rl;
            *(short8*)(Sb + (((size_t)(row0 + h * 64 + row_l)) << 10) + col0 + cs) =
                *(const short8*)&Ct[row_l * 128 + cs];
        }
        __syncthreads();
    }
}

/* ---- double softmax: one wave per row, in-place P2 ---- */
__global__ __launch_bounds__(256) void attn_rows(bf16* __restrict__ S, float* __restrict__ att_out) {
    int gr = blockIdx.x * 4 + (threadIdx.x >> 6);
    int t = gr & 1023;
    int lane = threadIdx.x & 63;
    bf16* row = S + ((size_t)gr << 10) + lane * 16;
    short8 r0 = *(const short8*)row;
    short8 r1 = *(const short8*)(row + 8);
    float v[16];
    #pragma unroll
    for (int i = 0; i < 8; i++) { v[i] = b2f(((bf16*)&r0)[i]); v[8 + i] = b2f(((bf16*)&r1)[i]); }
    float m = -INFINITY;
    #pragma unroll
    for (int i = 0; i < 16; i++) m = fmaxf(m, v[i]);
    #pragma unroll
    for (int off = 32; off; off >>= 1) m = fmaxf(m, __shfl_xor(m, off, 64));
    float s1 = 0.f, s2 = 0.f, dg = 0.f;
    int tloc = t - lane * 16;
    #pragma unroll
    for (int i = 0; i < 16; i++) {
        float e1 = expf(v[i] - m);
        float e2 = expf((v[i] - m) * INV_SCALE);
        s1 += e1; s2 += e2;
        if (i == tloc) dg = e1;
        v[i] = e2;
    }
    #pragma unroll
    for (int off = 32; off; off >>= 1) {
        s1 += __shfl_xor(s1, off, 64);
        s2 += __shfl_xor(s2, off, 64);
        dg += __shfl_xor(dg, off, 64);
    }
    if (lane == 0) att_out[gr] = (1.f - dg / s1) * INV_SCALE;
    float inv2 = 1.f / s2;
    #pragma unroll
    for (int i = 0; i < 8; i++) {
        ((bf16*)&r0)[i] = __float2bfloat16(v[i] * inv2);
        ((bf16*)&r1)[i] = __float2bfloat16(v[8 + i] * inv2);
    }
    *(short8*)row = r0;
    *(short8*)(row + 8) = r1;
}

/* ---- MFMA PV: out = P2 @ V * mvec, fp32 out ---- */
__global__ __launch_bounds__(256) void mfma_PV(const bf16* __restrict__ S, const bf16* __restrict__ valueT,
                                               const float* __restrict__ mvec, float* __restrict__ outp) {
    __shared__ short LB[8192];
    short* As = LB;
    short* Bs = LB + 4096;
    f32x4 acc[4][4] = {};
    int z = blockIdx.z;
    int row0 = blockIdx.x * 128, col0 = blockIdx.y * 128;
    const bf16* P2 = S + ((size_t)z << 20);
    const bf16* Vt = valueT + (size_t)z * NDP * NT;
    mfma_core(P2 + (size_t)row0 * NT, NT, Vt + (size_t)col0 * NT, NT, NT / 32, As, Bs, acc);
    const int tid = threadIdx.x, lane = tid & 63, wave = tid >> 6;
    const int wx = wave & 1, wy = wave >> 1, m16 = lane & 15, quad = lane >> 4;
    #pragma unroll
    for (int j = 0; j < 4; j++) {
        int c = col0 + wx * 64 + j * 16 + m16;
        if (c >= ND) continue;
        float mm = mvec[z * ND + c];
        #pragma unroll
        for (int i = 0; i < 4; i++) {
            #pragma unroll
            for (int reg = 0; reg < 4; reg++) {
                int r = row0 + wy * 64 + i * 16 + quad * 4 + reg;
                outp[((size_t)(z * NT + r)) * ND + c] = acc[i][j][reg] * mm;
            }
        }
    }
}

extern "C" void kernel_launch(void* const* d_in, const int* in_sizes, int n_in,
                              void* d_out, int out_size, void* d_ws, size_t ws_size,
                              hipStream_t stream) {
    const int*   words     = (const int*)d_in[0];
    const int*   pos       = (const int*)d_in[2];
    const int*   ner       = (const int*)d_in[3];
    const int*   subj_pos  = (const int*)d_in[4];
    const int*   obj_pos   = (const int*)d_in[5];
    const int*   chunks    = (const int*)d_in[6];
    const int*   on_path   = (const int*)d_in[7];
    const float* dep_feat  = (const float*)d_in[8];
    const float* emb_w     = (const float*)d_in[9];
    const float* pos_w     = (const float*)d_in[10];
    const float* ner_w     = (const float*)d_in[11];
    const float* chunk_w   = (const float*)d_in[12];
    const float* position_w= (const float*)d_in[13];
    const float* Wq_w      = (const float*)d_in[14];
    const float* Wq_b      = (const float*)d_in[15];
    const float* Wc_w      = (const float*)d_in[16];
    const float* Wc_b      = (const float*)d_in[17];
    const float* Wk_w      = (const float*)d_in[18];
    const float* Wk_b      = (const float*)d_in[19];
    const float* Wm_w      = (const float*)d_in[20];
    const float* Wm_b      = (const float*)d_in[21];
    const float* K_w       = (const float*)d_in[22];
    const float* K_b       = (const float*)d_in[23];
    const float* Q_w       = (const float*)d_in[24];
    const float* Q_b       = (const float*)d_in[25];
    const float* V_w       = (const float*)d_in[26];
    const float* V_b       = (const float*)d_in[27];

    float* out_main = (float*)d_out;
    float* out_att  = out_main + (size_t)NTOK * ND;

    /* ---- ws layout (~116 MB) ---- */
    char* wp = (char*)d_ws;
    float* subj = (float*)wp; wp += (size_t)NB * ND * 4;
    float* qb   = (float*)wp; wp += (size_t)NB * ND * 4;
    float* w2   = (float*)wp; wp += (size_t)NB * ND * 4;
    float* cb   = (float*)wp; wp += (size_t)NB * ND * 4;
    float* mv   = (float*)wp; wp += (size_t)NB * ND * 4;
    float* klog = (float*)wp; wp += (size_t)NB * NT * 4;
    float* kbuf = (float*)wp; wp += (size_t)NB * NT * 4;
    float* part = (float*)wp; wp += (size_t)NB * TSP * NDP * 4;
    bf16* g     = (bf16*)wp;  wp += (size_t)NTOK * NDP * 2;
    bf16* Wt    = (bf16*)wp;  wp += (size_t)3 * NDP * NDP * 2;
    bf16* kqv   = (bf16*)wp;  wp += (size_t)3 * NTOK * NDP * 2;  /* key | query | value */
    bf16* valT  = (bf16*)wp;  wp += (size_t)NTOK * NDP * 2;      /* Vt[b][c][s] */
    bf16* S     = (bf16*)wp;                                     /* NB<<20 bf16 = 32 MB */

    bf16* key   = kqv;
    bf16* query = kqv + (size_t)NTOK * NDP;
    bf16* value = kqv + (size_t)2 * NTOK * NDP;

    transpose_w3<<<dim3(16, 16, 3), 256, 0, stream>>>(K_w, Q_w, V_w, Wt);

    /* phase A */
    build_g<<<NTOK, 128, 0, stream>>>(words, pos, ner, chunks, subj_pos, obj_pos,
                                      on_path, dep_feat, emb_w, pos_w, ner_w,
                                      chunk_w, position_w, g);
    pool_part<<<dim3(NB, TSP), 64, 0, stream>>>(g, subj_pos, part);
    pool_reduce<<<NB, 512, 0, stream>>>(part, subj);
    gemv_part<<<dim3(NB, JS), 512, 0, stream>>>(subj, nullptr, Wq_w, part, 0);
    gemv_reduce<<<NB, 512, 0, stream>>>(part, Wq_b, nullptr, qb);
    gemv_part<<<dim3(NB, JS), 512, 0, stream>>>(qb, nullptr, Wc_w, part, 1);
    gemv_reduce<<<NB, 512, 0, stream>>>(part, Wc_b, Wk_w, w2);
    compute_klog<<<NTOK / 4, 256, 0, stream>>>(g, w2, Wk_b, klog);
    softmax_k<<<NB, 256, 0, stream>>>(klog, kbuf);
    c_part<<<dim3(NB, TSP), 64, 0, stream>>>(g, kbuf, part);
    c_reduce<<<NB, 512, 0, stream>>>(part, cb);
    gemv_part<<<dim3(NB, JS), 512, 0, stream>>>(cb, subj, Wm_w, part, 2);
    gemv_reduce<<<NB, 512, 0, stream>>>(part, Wm_b, nullptr, mv);

    /* phase B */
    mfma_proj3<<<dim3(NTOK / 128, NDP / 128, 3), 256, 0, stream>>>(g, Wt, K_b, Q_b, V_b, kqv);
    transpose_v<<<dim3(NT / 32, NDP / 32, NB), 256, 0, stream>>>(value, valT);
    mfma_S<<<dim3(NT / 128, NT / 128, NB), 256, 0, stream>>>(key, query, S);
    attn_rows<<<NTOK / 4, 256, 0, stream>>>(S, out_att);
    mfma_PV<<<dim3(NT / 128, NDP / 128, NB), 256, 0, stream>>>(S, valT, mv, out_main);

    (void)in_sizes; (void)n_in; (void)out_size; (void)ws_size;
}